// Round 15
// baseline (636.066 us; speedup 1.0000x reference)
//
#include <hip/hip_runtime.h>
#include <math.h>

#define NN    16384
#define NE    262144
#define NHEAD 4
#define HC    512
#define NG    8

typedef __bf16 bf16x8 __attribute__((ext_vector_type(8)));
typedef float floatx4 __attribute__((ext_vector_type(4)));
typedef float f32x2 __attribute__((ext_vector_type(2)));

__device__ __forceinline__ f32x2 sp2(float s) { return (f32x2){s, s}; }
__device__ __forceinline__ f32x2 pkmax(f32x2 a, f32x2 b) {
    f32x2 r; r.x = fmaxf(a.x, b.x); r.y = fmaxf(a.y, b.y); return r;
}

__device__ __forceinline__ unsigned short f2bf(float f) {
    union { float f; unsigned u; } v{f};
    unsigned r = v.u + 0x7FFFu + ((v.u >> 16) & 1u);  // RNE
    return (unsigned short)(r >> 16);
}

// unpack uint4 (8 packed bf16) -> 4 x f32x2 (channel pairs)
__device__ __forceinline__ void unpk8v(uint4 v, f32x2* f) {
    f[0] = (f32x2){__uint_as_float(v.x << 16), __uint_as_float(v.x & 0xFFFF0000u)};
    f[1] = (f32x2){__uint_as_float(v.y << 16), __uint_as_float(v.y & 0xFFFF0000u)};
    f[2] = (f32x2){__uint_as_float(v.z << 16), __uint_as_float(v.z & 0xFFFF0000u)};
    f[3] = (f32x2){__uint_as_float(v.w << 16), __uint_as_float(v.w & 0xFFFF0000u)};
}

// ---------- CSR build ----------
__global__ void k_hist(const int* __restrict__ dst, int* __restrict__ cnt) {
    int e = blockIdx.x * 256 + threadIdx.x;
    if (e < NE) atomicAdd(&cnt[dst[e]], 1);
}

__global__ __launch_bounds__(1024) void k_scan(const int* __restrict__ cnt,
                                               int* __restrict__ rp,
                                               int* __restrict__ offp,
                                               const int* __restrict__ batch,
                                               int* __restrict__ gcnt) {
    __shared__ int part[1024];
    int t = threadIdx.x;
    if (t < NG) {  // fused gcnt: batch sorted -> binary searches
        int lb[2];
#pragma unroll
        for (int q = 0; q < 2; q++) {
            int target = t + q;
            int lo = 0, hi = NN;
            while (lo < hi) {
                int mid = (lo + hi) >> 1;
                if (batch[mid] < target) lo = mid + 1; else hi = mid;
            }
            lb[q] = lo;
        }
        gcnt[t] = lb[1] - lb[0];
    }
    int base = t * 16;
    int loc[16];
    int s = 0;
#pragma unroll
    for (int i = 0; i < 16; i++) { loc[i] = s; s += cnt[base + i]; }
    part[t] = s;
    __syncthreads();
    for (int off = 1; off < 1024; off <<= 1) {
        int v = 0;
        if (t >= off) v = part[t - off];
        __syncthreads();
        if (t >= off) part[t] += v;
        __syncthreads();
    }
    int excl = (t == 0) ? 0 : part[t - 1];
#pragma unroll
    for (int i = 0; i < 16; i++) {
        int r = excl + loc[i];
        rp[base + i] = r;
        offp[base + i] = r;
    }
    if (t == 1023) rp[NN] = excl + s;
}

__global__ void k_fill(const int* __restrict__ dst, const int* __restrict__ src,
                       const float* __restrict__ ea, int* __restrict__ offp,
                       int* __restrict__ csrc, float2* __restrict__ ce) {
    int e = blockIdx.x * 256 + threadIdx.x;
    if (e < NE) {
        int d = dst[e];
        int pos = atomicAdd(&offp[d], 1);
        csrc[pos] = src[e];
        ce[pos] = *(const float2*)(ea + 2 * (size_t)e);
    }
}

// ---------- layer-1 linear (K=5), bf16 out, vectorized ----------
__global__ __launch_bounds__(256) void k_lin1(const float* __restrict__ x,
                                              const float* __restrict__ Wl,
                                              const float* __restrict__ Wr,
                                              unsigned short* __restrict__ xl,
                                              unsigned short* __restrict__ xr) {
    int n = blockIdx.x * 4 + (threadIdx.x >> 6);
    int lane = threadIdx.x & 63;
    int j0 = lane << 3;
    float xs[5];
#pragma unroll
    for (int k = 0; k < 5; k++) xs[k] = x[n * 5 + k];
    float al[8] = {}, ar[8] = {};
#pragma unroll
    for (int k = 0; k < 5; k++) {
        float4 wl0 = *(const float4*)(Wl + k * 512 + j0);
        float4 wl1 = *(const float4*)(Wl + k * 512 + j0 + 4);
        float4 wr0 = *(const float4*)(Wr + k * 512 + j0);
        float4 wr1 = *(const float4*)(Wr + k * 512 + j0 + 4);
        al[0] += xs[k] * wl0.x; al[1] += xs[k] * wl0.y; al[2] += xs[k] * wl0.z; al[3] += xs[k] * wl0.w;
        al[4] += xs[k] * wl1.x; al[5] += xs[k] * wl1.y; al[6] += xs[k] * wl1.z; al[7] += xs[k] * wl1.w;
        ar[0] += xs[k] * wr0.x; ar[1] += xs[k] * wr0.y; ar[2] += xs[k] * wr0.z; ar[3] += xs[k] * wr0.w;
        ar[4] += xs[k] * wr1.x; ar[5] += xs[k] * wr1.y; ar[6] += xs[k] * wr1.z; ar[7] += xs[k] * wr1.w;
    }
    ushort4 o0, o1;
    o0.x = f2bf(al[0]); o0.y = f2bf(al[1]); o0.z = f2bf(al[2]); o0.w = f2bf(al[3]);
    o1.x = f2bf(al[4]); o1.y = f2bf(al[5]); o1.z = f2bf(al[6]); o1.w = f2bf(al[7]);
    *(ushort4*)(xl + (size_t)n * 512 + j0) = o0;
    *(ushort4*)(xl + (size_t)n * 512 + j0 + 4) = o1;
    o0.x = f2bf(ar[0]); o0.y = f2bf(ar[1]); o0.z = f2bf(ar[2]); o0.w = f2bf(ar[3]);
    o1.x = f2bf(ar[4]); o1.y = f2bf(ar[5]); o1.z = f2bf(ar[6]); o1.w = f2bf(ar[7]);
    *(ushort4*)(xr + (size_t)n * 512 + j0) = o0;
    *(ushort4*)(xr + (size_t)n * 512 + j0 + 4) = o1;
}

// ---------- 4 weight transposes in one dispatch ----------
__global__ __launch_bounds__(256) void k_wt4(const float* __restrict__ W0,
                                             const float* __restrict__ W1,
                                             const float* __restrict__ W2,
                                             const float* __restrict__ W3,
                                             unsigned short* __restrict__ Wt2,
                                             unsigned short* __restrict__ Wt3) {
    __shared__ float tile[64][65];
    int bid = blockIdx.x;
    int mat = bid >> 6, sub = bid & 63;
    const float* W = (mat == 0) ? W0 : (mat == 1) ? W1 : (mat == 2) ? W2 : W3;
    unsigned short* Wt = (mat == 0) ? Wt2 : (mat == 1) ? (Wt2 + 512 * 512)
                       : (mat == 2) ? Wt3 : (Wt3 + 512 * 512);
    int n0 = (sub & 7) * 64, k0 = (sub >> 3) * 64;
    int lr = threadIdx.x >> 4;
    int lc = (threadIdx.x & 15) << 2;
    for (int r = lr; r < 64; r += 16) {
        float4 v = *(const float4*)(W + (size_t)(k0 + r) * 512 + n0 + lc);
        tile[r][lc] = v.x; tile[r][lc + 1] = v.y; tile[r][lc + 2] = v.z; tile[r][lc + 3] = v.w;
    }
    __syncthreads();
    for (int r = lr; r < 64; r += 16) {
        ushort4 o;
        o.x = f2bf(tile[lc + 0][r]); o.y = f2bf(tile[lc + 1][r]);
        o.z = f2bf(tile[lc + 2][r]); o.w = f2bf(tile[lc + 3][r]);
        *(ushort4*)(Wt + (size_t)(n0 + r) * 512 + k0 + lc) = o;
    }
}

// ---------- bf16 MFMA GEMM (LDK=72 padded, VGPR staging, XCD-swizzled grid) ----------
#define BM 128
#define BN 128
#define BK 64
#define LDK 72

__global__ __launch_bounds__(256) void k_gemm_bf16(
        const unsigned short* __restrict__ Ab,
        const unsigned short* __restrict__ Bt,
        unsigned short* __restrict__ xl, unsigned short* __restrict__ xr) {
    __shared__ unsigned short As[BM * LDK];
    __shared__ unsigned short Bs[BN * LDK];
    int t = threadIdx.x;
    int bid = blockIdx.x;
    int xcd = bid & 7, r = bid >> 3;
    int m0 = (xcd * 16 + (r & 15)) * BM;
    int n0 = (r >> 4) * BN;
    int wid = t >> 6, lane = t & 63;
    int wm = (wid >> 1) * 64, wn = (wid & 1) * 64;
    int lrow = lane & 15, quad = lane >> 4;
    floatx4 acc[4][4] = {};
    for (int k0 = 0; k0 < 512; k0 += BK) {
        __syncthreads();
#pragma unroll
        for (int it = 0; it < 4; it++) {
            int cid = it * 256 + t;
            int row = cid >> 3, ch = cid & 7;
            uint4 va = *(const uint4*)(Ab + (size_t)(m0 + row) * 512 + k0 + ch * 8);
            *(uint4*)&As[row * LDK + ch * 8] = va;
            uint4 vb = *(const uint4*)(Bt + (size_t)(n0 + row) * 512 + k0 + ch * 8);
            *(uint4*)&Bs[row * LDK + ch * 8] = vb;
        }
        __syncthreads();
#pragma unroll
        for (int ko = 0; ko < 2; ko++) {
            bf16x8 af[4], bfr[4];
#pragma unroll
            for (int i = 0; i < 4; i++) {
                af[i]  = *(const bf16x8*)&As[(wm + i * 16 + lrow) * LDK + ko * 32 + quad * 8];
                bfr[i] = *(const bf16x8*)&Bs[(wn + i * 16 + lrow) * LDK + ko * 32 + quad * 8];
            }
#pragma unroll
            for (int i = 0; i < 4; i++)
#pragma unroll
                for (int j = 0; j < 4; j++)
                    acc[i][j] = __builtin_amdgcn_mfma_f32_16x16x32_bf16(af[i], bfr[j], acc[i][j], 0, 0, 0);
        }
    }
#pragma unroll
    for (int i = 0; i < 4; i++) {
        int row = m0 + wm + i * 16 + quad * 4;
#pragma unroll
        for (int j = 0; j < 4; j++) {
            int col = n0 + wn + j * 16 + lrow;
            unsigned short* dstp = (col < 512) ? (xl + (size_t)row * 512 + col)
                                               : (xr + (size_t)row * 512 + (col - 512));
#pragma unroll
            for (int rr = 0; rr < 4; rr++) dstp[(size_t)rr * 512] = f2bf(acc[i][j][rr]);
        }
    }
}

// ---------- fused GATv2 edge phase: 2-wide edges, no-max softmax, packed-fp32 math ----------
__global__ __launch_bounds__(256) void k_attn(
        const unsigned short* __restrict__ xl, const unsigned short* __restrict__ xr,
        const int* __restrict__ rp, const int* __restrict__ csrc,
        const float2* __restrict__ ce, const float* __restrict__ We,
        const float* __restrict__ att, const float* __restrict__ bias,
        float* __restrict__ out) {
    int n = blockIdx.x * 4 + (threadIdx.x >> 6);
    int lane = threadIdx.x & 63;
    int c0 = lane << 3;
    f32x2 wv0[4], wv1[4], av[4], rv[4];
    {
        float4 a = *(const float4*)(We + c0), b = *(const float4*)(We + c0 + 4);
        wv0[0] = (f32x2){a.x, a.y}; wv0[1] = (f32x2){a.z, a.w};
        wv0[2] = (f32x2){b.x, b.y}; wv0[3] = (f32x2){b.z, b.w};
        a = *(const float4*)(We + 512 + c0); b = *(const float4*)(We + 512 + c0 + 4);
        wv1[0] = (f32x2){a.x, a.y}; wv1[1] = (f32x2){a.z, a.w};
        wv1[2] = (f32x2){b.x, b.y}; wv1[3] = (f32x2){b.z, b.w};
        a = *(const float4*)(att + c0); b = *(const float4*)(att + c0 + 4);
        av[0] = (f32x2){a.x, a.y}; av[1] = (f32x2){a.z, a.w};
        av[2] = (f32x2){b.x, b.y}; av[3] = (f32x2){b.z, b.w};
        uint4 vr = *(const uint4*)(xr + (size_t)n * 512 + c0);
        unpk8v(vr, rv);
    }
    float l = 0.f;
    f32x2 acc[4] = {sp2(0.f), sp2(0.f), sp2(0.f), sp2(0.f)};
    int beg = rp[n], end = rp[n + 1];
    uint4 cv0 = {}, cv1 = {};
    float2 ce0 = {}, ce1 = {};
    if (beg < end) {
        int i1 = (beg + 1 < end) ? beg + 1 : end - 1;
        cv0 = *(const uint4*)(xl + (size_t)csrc[beg] * 512 + c0);
        ce0 = ce[beg];
        cv1 = *(const uint4*)(xl + (size_t)csrc[i1] * 512 + c0);
        ce1 = ce[i1];
    }
    int i = beg;
    for (; i + 1 < end; i += 2) {
        uint4 a0 = cv0, a1 = cv1;
        float2 d0 = ce0, d1 = ce1;
        int q0 = i + 2, q1 = i + 3;
        q0 = (q0 < end) ? q0 : end - 1;
        q1 = (q1 < end) ? q1 : end - 1;
        cv0 = *(const uint4*)(xl + (size_t)csrc[q0] * 512 + c0);
        ce0 = ce[q0];
        cv1 = *(const uint4*)(xl + (size_t)csrc[q1] * 512 + c0);
        ce1 = ce[q1];
        f32x2 lv0[4], lv1[4];
        unpk8v(a0, lv0);
        unpk8v(a1, lv1);
        f32x2 d0x = sp2(d0.x), d0y = sp2(d0.y), d1x = sp2(d1.x), d1y = sp2(d1.y);
        f32x2 p0v = sp2(0.f), p1v = sp2(0.f);
#pragma unroll
        for (int j = 0; j < 4; j++) {
            f32x2 v0 = lv0[j] + rv[j] + d0x * wv0[j] + d0y * wv1[j];
            f32x2 v1 = lv1[j] + rv[j] + d1x * wv0[j] + d1y * wv1[j];
            v0 = pkmax(v0, sp2(0.2f) * v0);   // leaky_relu(0.2)
            v1 = pkmax(v1, sp2(0.2f) * v1);
            p0v += av[j] * v0;
            p1v += av[j] * v1;
        }
        float p0 = p0v.x + p0v.y;
        float p1 = p1v.x + p1v.y;
        p0 += __shfl_xor(p0, 1);  p1 += __shfl_xor(p1, 1);
        p0 += __shfl_xor(p0, 2);  p1 += __shfl_xor(p1, 2);
        p0 += __shfl_xor(p0, 4);  p1 += __shfl_xor(p1, 4);
        p0 += __shfl_xor(p0, 8);  p1 += __shfl_xor(p1, 8);
        float w0 = __expf(fminf(p0, 60.f));
        float w1 = __expf(fminf(p1, 60.f));
        l += w0 + w1;
        f32x2 w0v = sp2(w0), w1v = sp2(w1);
#pragma unroll
        for (int j = 0; j < 4; j++)
            acc[j] += w0v * lv0[j] + w1v * lv1[j];
    }
    if (i < end) {  // odd tail: cv0 holds edge end-1
        f32x2 lv[4];
        unpk8v(cv0, lv);
        f32x2 dx = sp2(ce0.x), dy = sp2(ce0.y);
        f32x2 pv = sp2(0.f);
#pragma unroll
        for (int j = 0; j < 4; j++) {
            f32x2 v = lv[j] + rv[j] + dx * wv0[j] + dy * wv1[j];
            v = pkmax(v, sp2(0.2f) * v);
            pv += av[j] * v;
        }
        float p = pv.x + pv.y;
        p += __shfl_xor(p, 1);
        p += __shfl_xor(p, 2);
        p += __shfl_xor(p, 4);
        p += __shfl_xor(p, 8);
        float w = __expf(fminf(p, 60.f));
        l += w;
        f32x2 wv = sp2(w);
#pragma unroll
        for (int j = 0; j < 4; j++) acc[j] += wv * lv[j];
    }
    float inv = 1.f / (l + 1e-16f);
    const float* bb = bias + c0;
    float4 b0 = *(const float4*)bb, b1 = *(const float4*)(bb + 4);
    float* o = out + (size_t)n * 512 + c0;
    *(float4*)o = make_float4(acc[0].x * inv + b0.x, acc[0].y * inv + b0.y,
                              acc[1].x * inv + b0.z, acc[1].y * inv + b0.w);
    *(float4*)(o + 4) = make_float4(acc[2].x * inv + b1.x, acc[2].y * inv + b1.y,
                                    acc[3].x * inv + b1.z, acc[3].y * inv + b1.w);
}

// ---------- BN stats (pure atomics, float4-coalesced) ----------
__global__ __launch_bounds__(256) void k_bnstat(const float* __restrict__ x,
                                                double* __restrict__ sum,
                                                double* __restrict__ sumsq) {
    int t = threadIdx.x;
    int r0 = blockIdx.x * 64;
    int c4 = (t & 127) << 2;   // 4 channels per thread
    int rr = t >> 7;           // 2-row interleave
    float s[4] = {}, q[4] = {};
    for (int r = r0 + rr; r < r0 + 64; r += 2) {
        float4 v = *(const float4*)(x + (size_t)r * 512 + c4);
        s[0] += v.x; q[0] += v.x * v.x;
        s[1] += v.y; q[1] += v.y * v.y;
        s[2] += v.z; q[2] += v.z * v.z;
        s[3] += v.w; q[3] += v.w * v.w;
    }
#pragma unroll
    for (int k = 0; k < 4; k++) {
        atomicAdd(sum + c4 + k, (double)s[k]);
        atomicAdd(sumsq + c4 + k, (double)q[k]);
    }
}

// ---------- BN finalize+apply + ELU + optional residual ----------
__global__ void k_bnapply(const float* __restrict__ v, const float* __restrict__ resid,
                          const double* __restrict__ sum, const double* __restrict__ sumsq,
                          const float* __restrict__ g, const float* __restrict__ beta,
                          float* __restrict__ out, unsigned short* __restrict__ outb) {
    int i = (blockIdx.x * 256 + threadIdx.x) << 2;
    int c = i & 511;
    float4 vv = *(const float4*)(v + i);
    double2 s01 = *(const double2*)(sum + c);
    double2 s23 = *(const double2*)(sum + c + 2);
    double2 q01 = *(const double2*)(sumsq + c);
    double2 q23 = *(const double2*)(sumsq + c + 2);
    float4 gg = *(const float4*)(g + c);
    float4 be = *(const float4*)(beta + c);
    const double invN = 1.0 / NN;
    double mu0 = s01.x * invN, mu1 = s01.y * invN, mu2 = s23.x * invN, mu3 = s23.y * invN;
    float sc0 = gg.x * rsqrtf((float)(q01.x * invN - mu0 * mu0) + 1e-5f);
    float sc1 = gg.y * rsqrtf((float)(q01.y * invN - mu1 * mu1) + 1e-5f);
    float sc2 = gg.z * rsqrtf((float)(q23.x * invN - mu2 * mu2) + 1e-5f);
    float sc3 = gg.w * rsqrtf((float)(q23.y * invN - mu3 * mu3) + 1e-5f);
    float y0 = (vv.x - (float)mu0) * sc0 + be.x;
    float y1 = (vv.y - (float)mu1) * sc1 + be.y;
    float y2 = (vv.z - (float)mu2) * sc2 + be.z;
    float y3 = (vv.w - (float)mu3) * sc3 + be.w;
    y0 = y0 > 0.f ? y0 : expm1f(y0);
    y1 = y1 > 0.f ? y1 : expm1f(y1);
    y2 = y2 > 0.f ? y2 : expm1f(y2);
    y3 = y3 > 0.f ? y3 : expm1f(y3);
    if (resid) {
        float4 rr = *(const float4*)(resid + i);
        y0 += rr.x; y1 += rr.y; y2 += rr.z; y3 += rr.w;
    }
    if (out) *(float4*)(out + i) = make_float4(y0, y1, y2, y3);
    if (outb) {
        ushort4 o;
        o.x = f2bf(y0); o.y = f2bf(y1); o.z = f2bf(y2); o.w = f2bf(y3);
        *(ushort4*)(outb + i) = o;
    }
}

// ---------- pooling (reads bf16 x3) ----------
__global__ __launch_bounds__(256) void k_pool(const unsigned short* __restrict__ xb,
                                              const int* __restrict__ batch,
                                              float* __restrict__ pooled) {
    __shared__ float lacc[NG][512];
    int t = threadIdx.x;
    for (int i = t; i < NG * 512; i += 256) ((float*)lacc)[i] = 0.f;
    __syncthreads();
    int r0 = blockIdx.x * 64;
    for (int r = r0; r < r0 + 64; r++) {
        int g = batch[r];
        lacc[g][t]       += __uint_as_float((unsigned)xb[(size_t)r * 512 + t] << 16);
        lacc[g][t + 256] += __uint_as_float((unsigned)xb[(size_t)r * 512 + t + 256] << 16);
    }
    __syncthreads();
    int gmin = batch[r0], gmax = batch[r0 + 63];
    for (int g = gmin; g <= gmax; g++)
        for (int i = t; i < 512; i += 256)
            atomicAdd(&pooled[g * 512 + i], lacc[g][i]);
}

// ---------- MLP head ----------
__global__ __launch_bounds__(256) void k_mlp1(const float* __restrict__ pooled,
                                              const int* __restrict__ gcnt,
                                              const float* __restrict__ W1,
                                              const float* __restrict__ b1,
                                              float* __restrict__ h1) {
    int g = blockIdx.x, o = threadIdx.x;
    float dot = 0.f;
    for (int c = 0; c < 512; c++) dot += pooled[g * 512 + c] * W1[c * 256 + o];
    float s = dot / (float)gcnt[g] + b1[o];
    h1[g * 256 + o] = fmaxf(s, 0.f);
}

__global__ __launch_bounds__(256) void k_head(const float* __restrict__ h1,
                                              const float* __restrict__ W2,
                                              const float* __restrict__ b2,
                                              const float* __restrict__ clsW,
                                              const float* __restrict__ clsb,
                                              float* __restrict__ outp) {
    __shared__ float es[256];
    int g = blockIdx.x, o = threadIdx.x;
    float s = b2[o];
    for (int c = 0; c < 256; c++) s += h1[g * 256 + c] * W2[c * 256 + o];
    outp[NG * 12 + g * 256 + o] = s;  // emb
    es[o] = s;
    __syncthreads();
    if (o < 12) {
        float lg = clsb[o];
        for (int c = 0; c < 256; c++) lg += es[c] * clsW[c * 12 + o];
        outp[g * 12 + o] = lg;  // logits
    }
}

extern "C" void kernel_launch(void* const* d_in, const int* in_sizes, int n_in,
                              void* d_out, int out_size, void* d_ws, size_t ws_size,
                              hipStream_t stream) {
    const float* x     = (const float*)d_in[0];
    const float* ea    = (const float*)d_in[1];
    const int*   ei    = (const int*)d_in[2];
    const int*   batch = (const int*)d_in[3];
    const int* src = ei;
    const int* dst = ei + NE;

    float* base = (float*)d_ws;
    size_t off = 0;
    auto alloc = [&](size_t n) -> float* {   // n = FLOAT count
        float* p = base + off;
        off += (n + 255) & ~(size_t)255;
        return p;
    };
    unsigned short* xl  = (unsigned short*)alloc((size_t)NN * 256);  // [NN,512] bf16
    unsigned short* xr  = (unsigned short*)alloc((size_t)NN * 256);
    float*    bufA  = alloc((size_t)NN * 512);
    float*    bufB  = alloc((size_t)NN * 512);
    unsigned short* Xb  = (unsigned short*)alloc((size_t)NN * 256);  // [NN,512] bf16
    unsigned short* Wt2 = (unsigned short*)alloc(512 * 1024 / 2);
    unsigned short* Wt3 = (unsigned short*)alloc(512 * 1024 / 2);
    int*      cnt   = (int*)alloc(NN);
    int*      rp    = (int*)alloc(NN + 1);
    int*      offp  = (int*)alloc(NN);
    int*      csrc  = (int*)alloc(NE);
    float2*   ce    = (float2*)alloc((size_t)NE * 2);
    double*   bsum3 = (double*)alloc(3 * 2048);  // 3 layers x (bsum[512]|bsq[512]) doubles
    float*    pooled= alloc(NG * 512);
    int*      gcnt  = (int*)alloc(NG);
    float*    h1    = alloc(NG * 256);
    float*    outp  = (float*)d_out;  // [0,96): logits, [96,2144): emb

    hipMemsetAsync(cnt, 0, NN * sizeof(int), stream);
    hipMemsetAsync(bsum3, 0, 3 * 2048 * sizeof(float), stream);
    hipMemsetAsync(pooled, 0, NG * 512 * sizeof(float), stream);
    k_hist<<<NE / 256, 256, 0, stream>>>(dst, cnt);
    k_scan<<<1, 1024, 0, stream>>>(cnt, rp, offp, batch, gcnt);
    k_fill<<<NE / 256, 256, 0, stream>>>(dst, src, ea, offp, csrc, ce);
    k_wt4<<<256, 256, 0, stream>>>((const float*)d_in[11], (const float*)d_in[12],
                                   (const float*)d_in[18], (const float*)d_in[19], Wt2, Wt3);

    float* X = bufA;
    float* Y = bufB;
    for (int l = 0; l < 3; l++) {
        const float* Wl  = (const float*)d_in[4 + l * 7 + 0];
        const float* Wr  = (const float*)d_in[4 + l * 7 + 1];
        const float* We  = (const float*)d_in[4 + l * 7 + 2];
        const float* att = (const float*)d_in[4 + l * 7 + 3];
        const float* cb  = (const float*)d_in[4 + l * 7 + 4];
        const float* bg  = (const float*)d_in[4 + l * 7 + 5];
        const float* bb  = (const float*)d_in[4 + l * 7 + 6];

        if (l == 0) {
            k_lin1<<<NN / 4, 256, 0, stream>>>(x, Wl, Wr, xl, xr);
        } else {
            k_gemm_bf16<<<1024, 256, 0, stream>>>(Xb, (l == 1) ? Wt2 : Wt3, xl, xr);
        }
        k_attn<<<NN / 4, 256, 0, stream>>>(xl, xr, rp, csrc, ce, We, att, cb, Y);

        double* bsum = bsum3 + l * 1024;
        double* bsq  = bsum + 512;
        k_bnstat<<<256, 256, 0, stream>>>(Y, bsum, bsq);
        k_bnapply<<<(size_t)NN * 512 / 1024, 256, 0, stream>>>(
            Y, (l == 0) ? nullptr : X, bsum, bsq, bg, bb,
            (l < 2) ? Y : nullptr, Xb);

        float* tmp = X; X = Y; Y = tmp;
    }

    k_pool<<<NN / 64, 256, 0, stream>>>(Xb, batch, pooled);

    const float* geW1 = (const float*)d_in[25];
    const float* geb1 = (const float*)d_in[26];
    const float* geW2 = (const float*)d_in[27];
    const float* geb2 = (const float*)d_in[28];
    const float* clsW = (const float*)d_in[29];
    const float* clsb = (const float*)d_in[30];

    k_mlp1<<<NG, 256, 0, stream>>>(pooled, gcnt, geW1, geb1, h1);
    k_head<<<NG, 256, 0, stream>>>(h1, geW2, geb2, clsW, clsb, outp);
}

// Round 16
// 541.541 us; speedup vs baseline: 1.1745x; 1.1745x over previous
//
#include <hip/hip_runtime.h>
#include <math.h>

#define NN    16384
#define NE    262144
#define NHEAD 4
#define HC    512
#define NG    8

typedef __bf16 bf16x8 __attribute__((ext_vector_type(8)));
typedef float floatx4 __attribute__((ext_vector_type(4)));
typedef float f32x2 __attribute__((ext_vector_type(2)));

__device__ __forceinline__ f32x2 sp2(float s) { return (f32x2){s, s}; }
__device__ __forceinline__ f32x2 pkmax(f32x2 a, f32x2 b) {
    f32x2 r; r.x = fmaxf(a.x, b.x); r.y = fmaxf(a.y, b.y); return r;
}

__device__ __forceinline__ unsigned short f2bf(float f) {
    union { float f; unsigned u; } v{f};
    unsigned r = v.u + 0x7FFFu + ((v.u >> 16) & 1u);  // RNE
    return (unsigned short)(r >> 16);
}

// unpack uint4 (8 packed bf16) -> 4 x f32x2 (channel pairs)
__device__ __forceinline__ void unpk8v(uint4 v, f32x2* f) {
    f[0] = (f32x2){__uint_as_float(v.x << 16), __uint_as_float(v.x & 0xFFFF0000u)};
    f[1] = (f32x2){__uint_as_float(v.y << 16), __uint_as_float(v.y & 0xFFFF0000u)};
    f[2] = (f32x2){__uint_as_float(v.z << 16), __uint_as_float(v.z & 0xFFFF0000u)};
    f[3] = (f32x2){__uint_as_float(v.w << 16), __uint_as_float(v.w & 0xFFFF0000u)};
}

// ---------- CSR build ----------
__global__ void k_hist(const int* __restrict__ dst, int* __restrict__ cnt) {
    int e = blockIdx.x * 256 + threadIdx.x;
    if (e < NE) atomicAdd(&cnt[dst[e]], 1);
}

__global__ __launch_bounds__(1024) void k_scan(const int* __restrict__ cnt,
                                               int* __restrict__ rp,
                                               int* __restrict__ offp,
                                               const int* __restrict__ batch,
                                               int* __restrict__ gcnt) {
    __shared__ int part[1024];
    int t = threadIdx.x;
    if (t < NG) {  // fused gcnt: batch sorted -> binary searches
        int lb[2];
#pragma unroll
        for (int q = 0; q < 2; q++) {
            int target = t + q;
            int lo = 0, hi = NN;
            while (lo < hi) {
                int mid = (lo + hi) >> 1;
                if (batch[mid] < target) lo = mid + 1; else hi = mid;
            }
            lb[q] = lo;
        }
        gcnt[t] = lb[1] - lb[0];
    }
    int base = t * 16;
    int loc[16];
    int s = 0;
#pragma unroll
    for (int i = 0; i < 16; i++) { loc[i] = s; s += cnt[base + i]; }
    part[t] = s;
    __syncthreads();
    for (int off = 1; off < 1024; off <<= 1) {
        int v = 0;
        if (t >= off) v = part[t - off];
        __syncthreads();
        if (t >= off) part[t] += v;
        __syncthreads();
    }
    int excl = (t == 0) ? 0 : part[t - 1];
#pragma unroll
    for (int i = 0; i < 16; i++) {
        int r = excl + loc[i];
        rp[base + i] = r;
        offp[base + i] = r;
    }
    if (t == 1023) rp[NN] = excl + s;
}

__global__ void k_fill(const int* __restrict__ dst, const int* __restrict__ src,
                       const float* __restrict__ ea, int* __restrict__ offp,
                       int* __restrict__ csrc, float2* __restrict__ ce) {
    int e = blockIdx.x * 256 + threadIdx.x;
    if (e < NE) {
        int d = dst[e];
        int pos = atomicAdd(&offp[d], 1);
        csrc[pos] = src[e];
        ce[pos] = *(const float2*)(ea + 2 * (size_t)e);
    }
}

// ---------- layer-1 linear (K=5), bf16 out, vectorized ----------
__global__ __launch_bounds__(256) void k_lin1(const float* __restrict__ x,
                                              const float* __restrict__ Wl,
                                              const float* __restrict__ Wr,
                                              unsigned short* __restrict__ xl,
                                              unsigned short* __restrict__ xr) {
    int n = blockIdx.x * 4 + (threadIdx.x >> 6);
    int lane = threadIdx.x & 63;
    int j0 = lane << 3;
    float xs[5];
#pragma unroll
    for (int k = 0; k < 5; k++) xs[k] = x[n * 5 + k];
    float al[8] = {}, ar[8] = {};
#pragma unroll
    for (int k = 0; k < 5; k++) {
        float4 wl0 = *(const float4*)(Wl + k * 512 + j0);
        float4 wl1 = *(const float4*)(Wl + k * 512 + j0 + 4);
        float4 wr0 = *(const float4*)(Wr + k * 512 + j0);
        float4 wr1 = *(const float4*)(Wr + k * 512 + j0 + 4);
        al[0] += xs[k] * wl0.x; al[1] += xs[k] * wl0.y; al[2] += xs[k] * wl0.z; al[3] += xs[k] * wl0.w;
        al[4] += xs[k] * wl1.x; al[5] += xs[k] * wl1.y; al[6] += xs[k] * wl1.z; al[7] += xs[k] * wl1.w;
        ar[0] += xs[k] * wr0.x; ar[1] += xs[k] * wr0.y; ar[2] += xs[k] * wr0.z; ar[3] += xs[k] * wr0.w;
        ar[4] += xs[k] * wr1.x; ar[5] += xs[k] * wr1.y; ar[6] += xs[k] * wr1.z; ar[7] += xs[k] * wr1.w;
    }
    ushort4 o0, o1;
    o0.x = f2bf(al[0]); o0.y = f2bf(al[1]); o0.z = f2bf(al[2]); o0.w = f2bf(al[3]);
    o1.x = f2bf(al[4]); o1.y = f2bf(al[5]); o1.z = f2bf(al[6]); o1.w = f2bf(al[7]);
    *(ushort4*)(xl + (size_t)n * 512 + j0) = o0;
    *(ushort4*)(xl + (size_t)n * 512 + j0 + 4) = o1;
    o0.x = f2bf(ar[0]); o0.y = f2bf(ar[1]); o0.z = f2bf(ar[2]); o0.w = f2bf(ar[3]);
    o1.x = f2bf(ar[4]); o1.y = f2bf(ar[5]); o1.z = f2bf(ar[6]); o1.w = f2bf(ar[7]);
    *(ushort4*)(xr + (size_t)n * 512 + j0) = o0;
    *(ushort4*)(xr + (size_t)n * 512 + j0 + 4) = o1;
}

// ---------- 4 weight transposes in one dispatch ----------
__global__ __launch_bounds__(256) void k_wt4(const float* __restrict__ W0,
                                             const float* __restrict__ W1,
                                             const float* __restrict__ W2,
                                             const float* __restrict__ W3,
                                             unsigned short* __restrict__ Wt2,
                                             unsigned short* __restrict__ Wt3) {
    __shared__ float tile[64][65];
    int bid = blockIdx.x;
    int mat = bid >> 6, sub = bid & 63;
    const float* W = (mat == 0) ? W0 : (mat == 1) ? W1 : (mat == 2) ? W2 : W3;
    unsigned short* Wt = (mat == 0) ? Wt2 : (mat == 1) ? (Wt2 + 512 * 512)
                       : (mat == 2) ? Wt3 : (Wt3 + 512 * 512);
    int n0 = (sub & 7) * 64, k0 = (sub >> 3) * 64;
    int lr = threadIdx.x >> 4;
    int lc = (threadIdx.x & 15) << 2;
    for (int r = lr; r < 64; r += 16) {
        float4 v = *(const float4*)(W + (size_t)(k0 + r) * 512 + n0 + lc);
        tile[r][lc] = v.x; tile[r][lc + 1] = v.y; tile[r][lc + 2] = v.z; tile[r][lc + 3] = v.w;
    }
    __syncthreads();
    for (int r = lr; r < 64; r += 16) {
        ushort4 o;
        o.x = f2bf(tile[lc + 0][r]); o.y = f2bf(tile[lc + 1][r]);
        o.z = f2bf(tile[lc + 2][r]); o.w = f2bf(tile[lc + 3][r]);
        *(ushort4*)(Wt + (size_t)(n0 + r) * 512 + k0 + lc) = o;
    }
}

// ---------- bf16 MFMA GEMM (LDK=72 padded, VGPR staging, XCD-swizzled grid) ----------
#define BM 128
#define BN 128
#define BK 64
#define LDK 72

__global__ __launch_bounds__(256) void k_gemm_bf16(
        const unsigned short* __restrict__ Ab,
        const unsigned short* __restrict__ Bt,
        unsigned short* __restrict__ xl, unsigned short* __restrict__ xr) {
    __shared__ unsigned short As[BM * LDK];
    __shared__ unsigned short Bs[BN * LDK];
    int t = threadIdx.x;
    int bid = blockIdx.x;
    int xcd = bid & 7, r = bid >> 3;
    int m0 = (xcd * 16 + (r & 15)) * BM;
    int n0 = (r >> 4) * BN;
    int wid = t >> 6, lane = t & 63;
    int wm = (wid >> 1) * 64, wn = (wid & 1) * 64;
    int lrow = lane & 15, quad = lane >> 4;
    floatx4 acc[4][4] = {};
    for (int k0 = 0; k0 < 512; k0 += BK) {
        __syncthreads();
#pragma unroll
        for (int it = 0; it < 4; it++) {
            int cid = it * 256 + t;
            int row = cid >> 3, ch = cid & 7;
            uint4 va = *(const uint4*)(Ab + (size_t)(m0 + row) * 512 + k0 + ch * 8);
            *(uint4*)&As[row * LDK + ch * 8] = va;
            uint4 vb = *(const uint4*)(Bt + (size_t)(n0 + row) * 512 + k0 + ch * 8);
            *(uint4*)&Bs[row * LDK + ch * 8] = vb;
        }
        __syncthreads();
#pragma unroll
        for (int ko = 0; ko < 2; ko++) {
            bf16x8 af[4], bfr[4];
#pragma unroll
            for (int i = 0; i < 4; i++) {
                af[i]  = *(const bf16x8*)&As[(wm + i * 16 + lrow) * LDK + ko * 32 + quad * 8];
                bfr[i] = *(const bf16x8*)&Bs[(wn + i * 16 + lrow) * LDK + ko * 32 + quad * 8];
            }
#pragma unroll
            for (int i = 0; i < 4; i++)
#pragma unroll
                for (int j = 0; j < 4; j++)
                    acc[i][j] = __builtin_amdgcn_mfma_f32_16x16x32_bf16(af[i], bfr[j], acc[i][j], 0, 0, 0);
        }
    }
#pragma unroll
    for (int i = 0; i < 4; i++) {
        int row = m0 + wm + i * 16 + quad * 4;
#pragma unroll
        for (int j = 0; j < 4; j++) {
            int col = n0 + wn + j * 16 + lrow;
            unsigned short* dstp = (col < 512) ? (xl + (size_t)row * 512 + col)
                                               : (xr + (size_t)row * 512 + (col - 512));
#pragma unroll
            for (int rr = 0; rr < 4; rr++) dstp[(size_t)rr * 512] = f2bf(acc[i][j][rr]);
        }
    }
}

// ---------- fused GATv2 edge phase: 2-wide edges, no-max softmax, packed-fp32 math ----------
__global__ __launch_bounds__(256) void k_attn(
        const unsigned short* __restrict__ xl, const unsigned short* __restrict__ xr,
        const int* __restrict__ rp, const int* __restrict__ csrc,
        const float2* __restrict__ ce, const float* __restrict__ We,
        const float* __restrict__ att, const float* __restrict__ bias,
        float* __restrict__ out) {
    int n = blockIdx.x * 4 + (threadIdx.x >> 6);
    int lane = threadIdx.x & 63;
    int c0 = lane << 3;
    f32x2 wv0[4], wv1[4], av[4], rv[4];
    {
        float4 a = *(const float4*)(We + c0), b = *(const float4*)(We + c0 + 4);
        wv0[0] = (f32x2){a.x, a.y}; wv0[1] = (f32x2){a.z, a.w};
        wv0[2] = (f32x2){b.x, b.y}; wv0[3] = (f32x2){b.z, b.w};
        a = *(const float4*)(We + 512 + c0); b = *(const float4*)(We + 512 + c0 + 4);
        wv1[0] = (f32x2){a.x, a.y}; wv1[1] = (f32x2){a.z, a.w};
        wv1[2] = (f32x2){b.x, b.y}; wv1[3] = (f32x2){b.z, b.w};
        a = *(const float4*)(att + c0); b = *(const float4*)(att + c0 + 4);
        av[0] = (f32x2){a.x, a.y}; av[1] = (f32x2){a.z, a.w};
        av[2] = (f32x2){b.x, b.y}; av[3] = (f32x2){b.z, b.w};
        uint4 vr = *(const uint4*)(xr + (size_t)n * 512 + c0);
        unpk8v(vr, rv);
    }
    float l = 0.f;
    f32x2 acc[4] = {sp2(0.f), sp2(0.f), sp2(0.f), sp2(0.f)};
    int beg = rp[n], end = rp[n + 1];
    uint4 cv0 = {}, cv1 = {};
    float2 ce0 = {}, ce1 = {};
    if (beg < end) {
        int i1 = (beg + 1 < end) ? beg + 1 : end - 1;
        cv0 = *(const uint4*)(xl + (size_t)csrc[beg] * 512 + c0);
        ce0 = ce[beg];
        cv1 = *(const uint4*)(xl + (size_t)csrc[i1] * 512 + c0);
        ce1 = ce[i1];
    }
    int i = beg;
    for (; i + 1 < end; i += 2) {
        uint4 a0 = cv0, a1 = cv1;
        float2 d0 = ce0, d1 = ce1;
        int q0 = i + 2, q1 = i + 3;
        q0 = (q0 < end) ? q0 : end - 1;
        q1 = (q1 < end) ? q1 : end - 1;
        cv0 = *(const uint4*)(xl + (size_t)csrc[q0] * 512 + c0);
        ce0 = ce[q0];
        cv1 = *(const uint4*)(xl + (size_t)csrc[q1] * 512 + c0);
        ce1 = ce[q1];
        f32x2 lv0[4], lv1[4];
        unpk8v(a0, lv0);
        unpk8v(a1, lv1);
        f32x2 d0x = sp2(d0.x), d0y = sp2(d0.y), d1x = sp2(d1.x), d1y = sp2(d1.y);
        f32x2 p0v = sp2(0.f), p1v = sp2(0.f);
#pragma unroll
        for (int j = 0; j < 4; j++) {
            f32x2 v0 = lv0[j] + rv[j] + d0x * wv0[j] + d0y * wv1[j];
            f32x2 v1 = lv1[j] + rv[j] + d1x * wv0[j] + d1y * wv1[j];
            v0 = pkmax(v0, sp2(0.2f) * v0);   // leaky_relu(0.2)
            v1 = pkmax(v1, sp2(0.2f) * v1);
            p0v += av[j] * v0;
            p1v += av[j] * v1;
        }
        float p0 = p0v.x + p0v.y;
        float p1 = p1v.x + p1v.y;
        p0 += __shfl_xor(p0, 1);  p1 += __shfl_xor(p1, 1);
        p0 += __shfl_xor(p0, 2);  p1 += __shfl_xor(p1, 2);
        p0 += __shfl_xor(p0, 4);  p1 += __shfl_xor(p1, 4);
        p0 += __shfl_xor(p0, 8);  p1 += __shfl_xor(p1, 8);
        float w0 = __expf(fminf(p0, 60.f));
        float w1 = __expf(fminf(p1, 60.f));
        l += w0 + w1;
        f32x2 w0v = sp2(w0), w1v = sp2(w1);
#pragma unroll
        for (int j = 0; j < 4; j++)
            acc[j] += w0v * lv0[j] + w1v * lv1[j];
    }
    if (i < end) {  // odd tail: cv0 holds edge end-1
        f32x2 lv[4];
        unpk8v(cv0, lv);
        f32x2 dx = sp2(ce0.x), dy = sp2(ce0.y);
        f32x2 pv = sp2(0.f);
#pragma unroll
        for (int j = 0; j < 4; j++) {
            f32x2 v = lv[j] + rv[j] + dx * wv0[j] + dy * wv1[j];
            v = pkmax(v, sp2(0.2f) * v);
            pv += av[j] * v;
        }
        float p = pv.x + pv.y;
        p += __shfl_xor(p, 1);
        p += __shfl_xor(p, 2);
        p += __shfl_xor(p, 4);
        p += __shfl_xor(p, 8);
        float w = __expf(fminf(p, 60.f));
        l += w;
        f32x2 wv = sp2(w);
#pragma unroll
        for (int j = 0; j < 4; j++) acc[j] += wv * lv[j];
    }
    float inv = 1.f / (l + 1e-16f);
    const float* bb = bias + c0;
    float4 b0 = *(const float4*)bb, b1 = *(const float4*)(bb + 4);
    float* o = out + (size_t)n * 512 + c0;
    *(float4*)o = make_float4(acc[0].x * inv + b0.x, acc[0].y * inv + b0.y,
                              acc[1].x * inv + b0.z, acc[1].y * inv + b0.w);
    *(float4*)(o + 4) = make_float4(acc[2].x * inv + b1.x, acc[2].y * inv + b1.y,
                                    acc[3].x * inv + b1.z, acc[3].y * inv + b1.w);
}

// ---------- BN stats stage A: per-block partials, plain stores (NO atomics) ----------
__global__ __launch_bounds__(256) void k_bnstatA(const float* __restrict__ x,
                                                 float* __restrict__ psum,
                                                 float* __restrict__ psq) {
    int t = threadIdx.x;
    int r0 = blockIdx.x * 64;
    float s0 = 0.f, s1 = 0.f, q0 = 0.f, q1 = 0.f;
    for (int r = r0; r < r0 + 64; r++) {
        float v0 = x[(size_t)r * 512 + t];
        float v1 = x[(size_t)r * 512 + t + 256];
        s0 += v0; q0 += v0 * v0;
        s1 += v1; q1 += v1 * v1;
    }
    int b = blockIdx.x * 512;
    psum[b + t] = s0; psum[b + t + 256] = s1;
    psq [b + t] = q0; psq [b + t + 256] = q1;
}

// ---------- BN stats stage B: fp64 reduce 256 partials per channel ----------
__global__ __launch_bounds__(512) void k_bnred(const float* __restrict__ psum,
                                               const float* __restrict__ psq,
                                               double* __restrict__ bsum,
                                               double* __restrict__ bsq) {
    int c = threadIdx.x;  // 512 channels
    double s = 0.0, q = 0.0;
    for (int b = 0; b < 256; b++) {
        s += (double)psum[b * 512 + c];
        q += (double)psq[b * 512 + c];
    }
    bsum[c] = s;
    bsq[c] = q;
}

// ---------- BN finalize+apply + ELU + optional residual ----------
__global__ void k_bnapply(const float* __restrict__ v, const float* __restrict__ resid,
                          const double* __restrict__ sum, const double* __restrict__ sumsq,
                          const float* __restrict__ g, const float* __restrict__ beta,
                          float* __restrict__ out, unsigned short* __restrict__ outb) {
    int i = (blockIdx.x * 256 + threadIdx.x) << 2;
    int c = i & 511;
    float4 vv = *(const float4*)(v + i);
    double2 s01 = *(const double2*)(sum + c);
    double2 s23 = *(const double2*)(sum + c + 2);
    double2 q01 = *(const double2*)(sumsq + c);
    double2 q23 = *(const double2*)(sumsq + c + 2);
    float4 gg = *(const float4*)(g + c);
    float4 be = *(const float4*)(beta + c);
    const double invN = 1.0 / NN;
    double mu0 = s01.x * invN, mu1 = s01.y * invN, mu2 = s23.x * invN, mu3 = s23.y * invN;
    float sc0 = gg.x * rsqrtf((float)(q01.x * invN - mu0 * mu0) + 1e-5f);
    float sc1 = gg.y * rsqrtf((float)(q01.y * invN - mu1 * mu1) + 1e-5f);
    float sc2 = gg.z * rsqrtf((float)(q23.x * invN - mu2 * mu2) + 1e-5f);
    float sc3 = gg.w * rsqrtf((float)(q23.y * invN - mu3 * mu3) + 1e-5f);
    float y0 = (vv.x - (float)mu0) * sc0 + be.x;
    float y1 = (vv.y - (float)mu1) * sc1 + be.y;
    float y2 = (vv.z - (float)mu2) * sc2 + be.z;
    float y3 = (vv.w - (float)mu3) * sc3 + be.w;
    y0 = y0 > 0.f ? y0 : expm1f(y0);
    y1 = y1 > 0.f ? y1 : expm1f(y1);
    y2 = y2 > 0.f ? y2 : expm1f(y2);
    y3 = y3 > 0.f ? y3 : expm1f(y3);
    if (resid) {
        float4 rr = *(const float4*)(resid + i);
        y0 += rr.x; y1 += rr.y; y2 += rr.z; y3 += rr.w;
    }
    if (out) *(float4*)(out + i) = make_float4(y0, y1, y2, y3);
    if (outb) {
        ushort4 o;
        o.x = f2bf(y0); o.y = f2bf(y1); o.z = f2bf(y2); o.w = f2bf(y3);
        *(ushort4*)(outb + i) = o;
    }
}

// ---------- pooling (reads bf16 x3) ----------
__global__ __launch_bounds__(256) void k_pool(const unsigned short* __restrict__ xb,
                                              const int* __restrict__ batch,
                                              float* __restrict__ pooled) {
    __shared__ float lacc[NG][512];
    int t = threadIdx.x;
    for (int i = t; i < NG * 512; i += 256) ((float*)lacc)[i] = 0.f;
    __syncthreads();
    int r0 = blockIdx.x * 64;
    for (int r = r0; r < r0 + 64; r++) {
        int g = batch[r];
        lacc[g][t]       += __uint_as_float((unsigned)xb[(size_t)r * 512 + t] << 16);
        lacc[g][t + 256] += __uint_as_float((unsigned)xb[(size_t)r * 512 + t + 256] << 16);
    }
    __syncthreads();
    int gmin = batch[r0], gmax = batch[r0 + 63];
    for (int g = gmin; g <= gmax; g++)
        for (int i = t; i < 512; i += 256)
            atomicAdd(&pooled[g * 512 + i], lacc[g][i]);
}

// ---------- MLP head ----------
__global__ __launch_bounds__(256) void k_mlp1(const float* __restrict__ pooled,
                                              const int* __restrict__ gcnt,
                                              const float* __restrict__ W1,
                                              const float* __restrict__ b1,
                                              float* __restrict__ h1) {
    int g = blockIdx.x, o = threadIdx.x;
    float dot = 0.f;
    for (int c = 0; c < 512; c++) dot += pooled[g * 512 + c] * W1[c * 256 + o];
    float s = dot / (float)gcnt[g] + b1[o];
    h1[g * 256 + o] = fmaxf(s, 0.f);
}

__global__ __launch_bounds__(256) void k_head(const float* __restrict__ h1,
                                              const float* __restrict__ W2,
                                              const float* __restrict__ b2,
                                              const float* __restrict__ clsW,
                                              const float* __restrict__ clsb,
                                              float* __restrict__ outp) {
    __shared__ float es[256];
    int g = blockIdx.x, o = threadIdx.x;
    float s = b2[o];
    for (int c = 0; c < 256; c++) s += h1[g * 256 + c] * W2[c * 256 + o];
    outp[NG * 12 + g * 256 + o] = s;  // emb
    es[o] = s;
    __syncthreads();
    if (o < 12) {
        float lg = clsb[o];
        for (int c = 0; c < 256; c++) lg += es[c] * clsW[c * 12 + o];
        outp[g * 12 + o] = lg;  // logits
    }
}

extern "C" void kernel_launch(void* const* d_in, const int* in_sizes, int n_in,
                              void* d_out, int out_size, void* d_ws, size_t ws_size,
                              hipStream_t stream) {
    const float* x     = (const float*)d_in[0];
    const float* ea    = (const float*)d_in[1];
    const int*   ei    = (const int*)d_in[2];
    const int*   batch = (const int*)d_in[3];
    const int* src = ei;
    const int* dst = ei + NE;

    float* base = (float*)d_ws;
    size_t off = 0;
    auto alloc = [&](size_t n) -> float* {   // n = FLOAT count
        float* p = base + off;
        off += (n + 255) & ~(size_t)255;
        return p;
    };
    unsigned short* xl  = (unsigned short*)alloc((size_t)NN * 256);  // [NN,512] bf16
    unsigned short* xr  = (unsigned short*)alloc((size_t)NN * 256);
    float*    bufA  = alloc((size_t)NN * 512);
    float*    bufB  = alloc((size_t)NN * 512);
    unsigned short* Xb  = (unsigned short*)alloc((size_t)NN * 256);  // [NN,512] bf16
    unsigned short* Wt2 = (unsigned short*)alloc(512 * 1024 / 2);
    unsigned short* Wt3 = (unsigned short*)alloc(512 * 1024 / 2);
    int*      cnt   = (int*)alloc(NN);
    int*      rp    = (int*)alloc(NN + 1);
    int*      offp  = (int*)alloc(NN);
    int*      csrc  = (int*)alloc(NE);
    float2*   ce    = (float2*)alloc((size_t)NE * 2);
    float*    psum  = alloc(256 * 512);   // per-block partials (no atomics)
    float*    psq   = alloc(256 * 512);
    double*   bsum  = (double*)alloc(1024);  // 512 doubles
    double*   bsq   = (double*)alloc(1024);
    float*    pooled= alloc(NG * 512);
    int*      gcnt  = (int*)alloc(NG);
    float*    h1    = alloc(NG * 256);
    float*    outp  = (float*)d_out;  // [0,96): logits, [96,2144): emb

    hipMemsetAsync(cnt, 0, NN * sizeof(int), stream);
    hipMemsetAsync(pooled, 0, NG * 512 * sizeof(float), stream);
    k_hist<<<NE / 256, 256, 0, stream>>>(dst, cnt);
    k_scan<<<1, 1024, 0, stream>>>(cnt, rp, offp, batch, gcnt);
    k_fill<<<NE / 256, 256, 0, stream>>>(dst, src, ea, offp, csrc, ce);
    k_wt4<<<256, 256, 0, stream>>>((const float*)d_in[11], (const float*)d_in[12],
                                   (const float*)d_in[18], (const float*)d_in[19], Wt2, Wt3);

    float* X = bufA;
    float* Y = bufB;
    for (int l = 0; l < 3; l++) {
        const float* Wl  = (const float*)d_in[4 + l * 7 + 0];
        const float* Wr  = (const float*)d_in[4 + l * 7 + 1];
        const float* We  = (const float*)d_in[4 + l * 7 + 2];
        const float* att = (const float*)d_in[4 + l * 7 + 3];
        const float* cb  = (const float*)d_in[4 + l * 7 + 4];
        const float* bg  = (const float*)d_in[4 + l * 7 + 5];
        const float* bb  = (const float*)d_in[4 + l * 7 + 6];

        if (l == 0) {
            k_lin1<<<NN / 4, 256, 0, stream>>>(x, Wl, Wr, xl, xr);
        } else {
            k_gemm_bf16<<<1024, 256, 0, stream>>>(Xb, (l == 1) ? Wt2 : Wt3, xl, xr);
        }
        k_attn<<<NN / 4, 256, 0, stream>>>(xl, xr, rp, csrc, ce, We, att, cb, Y);

        k_bnstatA<<<256, 256, 0, stream>>>(Y, psum, psq);
        k_bnred<<<1, 512, 0, stream>>>(psum, psq, bsum, bsq);
        k_bnapply<<<(size_t)NN * 512 / 1024, 256, 0, stream>>>(
            Y, (l == 0) ? nullptr : X, bsum, bsq, bg, bb,
            (l < 2) ? Y : nullptr, Xb);

        float* tmp = X; X = Y; Y = tmp;
    }

    k_pool<<<NN / 64, 256, 0, stream>>>(Xb, batch, pooled);

    const float* geW1 = (const float*)d_in[25];
    const float* geb1 = (const float*)d_in[26];
    const float* geW2 = (const float*)d_in[27];
    const float* geb2 = (const float*)d_in[28];
    const float* clsW = (const float*)d_in[29];
    const float* clsb = (const float*)d_in[30];

    k_mlp1<<<NG, 256, 0, stream>>>(pooled, gcnt, geW1, geb1, h1);
    k_head<<<NG, 256, 0, stream>>>(h1, geW2, geb2, clsW, clsb, outp);
}

// Round 17
// 502.915 us; speedup vs baseline: 1.2648x; 1.0768x over previous
//
#include <hip/hip_runtime.h>
#include <math.h>

#define NN    16384
#define NE    262144
#define NHEAD 4
#define HC    512
#define NG    8

typedef __bf16 bf16x8 __attribute__((ext_vector_type(8)));
typedef float floatx4 __attribute__((ext_vector_type(4)));
typedef float f32x2 __attribute__((ext_vector_type(2)));

__device__ __forceinline__ f32x2 sp2(float s) { return (f32x2){s, s}; }
__device__ __forceinline__ f32x2 pkmax(f32x2 a, f32x2 b) {
    f32x2 r; r.x = fmaxf(a.x, b.x); r.y = fmaxf(a.y, b.y); return r;
}

__device__ __forceinline__ unsigned short f2bf(float f) {
    union { float f; unsigned u; } v{f};
    unsigned r = v.u + 0x7FFFu + ((v.u >> 16) & 1u);  // RNE
    return (unsigned short)(r >> 16);
}

// unpack uint4 (8 packed bf16) -> 4 x f32x2 (channel pairs)
__device__ __forceinline__ void unpk8v(uint4 v, f32x2* f) {
    f[0] = (f32x2){__uint_as_float(v.x << 16), __uint_as_float(v.x & 0xFFFF0000u)};
    f[1] = (f32x2){__uint_as_float(v.y << 16), __uint_as_float(v.y & 0xFFFF0000u)};
    f[2] = (f32x2){__uint_as_float(v.z << 16), __uint_as_float(v.z & 0xFFFF0000u)};
    f[3] = (f32x2){__uint_as_float(v.w << 16), __uint_as_float(v.w & 0xFFFF0000u)};
}

// ---------- CSR build ----------
__global__ void k_hist(const int* __restrict__ dst, int* __restrict__ cnt) {
    int e = blockIdx.x * 256 + threadIdx.x;
    if (e < NE) atomicAdd(&cnt[dst[e]], 1);
}

__global__ __launch_bounds__(1024) void k_scan(const int* __restrict__ cnt,
                                               int* __restrict__ rp,
                                               int* __restrict__ offp,
                                               const int* __restrict__ batch,
                                               int* __restrict__ gcnt) {
    __shared__ int part[1024];
    int t = threadIdx.x;
    if (t < NG) {  // fused gcnt: batch sorted -> binary searches
        int lb[2];
#pragma unroll
        for (int q = 0; q < 2; q++) {
            int target = t + q;
            int lo = 0, hi = NN;
            while (lo < hi) {
                int mid = (lo + hi) >> 1;
                if (batch[mid] < target) lo = mid + 1; else hi = mid;
            }
            lb[q] = lo;
        }
        gcnt[t] = lb[1] - lb[0];
    }
    int base = t * 16;
    int loc[16];
    int s = 0;
#pragma unroll
    for (int i = 0; i < 16; i++) { loc[i] = s; s += cnt[base + i]; }
    part[t] = s;
    __syncthreads();
    for (int off = 1; off < 1024; off <<= 1) {
        int v = 0;
        if (t >= off) v = part[t - off];
        __syncthreads();
        if (t >= off) part[t] += v;
        __syncthreads();
    }
    int excl = (t == 0) ? 0 : part[t - 1];
#pragma unroll
    for (int i = 0; i < 16; i++) {
        int r = excl + loc[i];
        rp[base + i] = r;
        offp[base + i] = r;
    }
    if (t == 1023) rp[NN] = excl + s;
}

__global__ void k_fill(const int* __restrict__ dst, const int* __restrict__ src,
                       const float* __restrict__ ea, int* __restrict__ offp,
                       int* __restrict__ csrc, float2* __restrict__ ce) {
    int e = blockIdx.x * 256 + threadIdx.x;
    if (e < NE) {
        int d = dst[e];
        int pos = atomicAdd(&offp[d], 1);
        csrc[pos] = src[e];
        ce[pos] = *(const float2*)(ea + 2 * (size_t)e);
    }
}

// ---------- layer-1 linear (K=5), bf16 out, vectorized ----------
__global__ __launch_bounds__(256) void k_lin1(const float* __restrict__ x,
                                              const float* __restrict__ Wl,
                                              const float* __restrict__ Wr,
                                              unsigned short* __restrict__ xl,
                                              unsigned short* __restrict__ xr) {
    int n = blockIdx.x * 4 + (threadIdx.x >> 6);
    int lane = threadIdx.x & 63;
    int j0 = lane << 3;
    float xs[5];
#pragma unroll
    for (int k = 0; k < 5; k++) xs[k] = x[n * 5 + k];
    float al[8] = {}, ar[8] = {};
#pragma unroll
    for (int k = 0; k < 5; k++) {
        float4 wl0 = *(const float4*)(Wl + k * 512 + j0);
        float4 wl1 = *(const float4*)(Wl + k * 512 + j0 + 4);
        float4 wr0 = *(const float4*)(Wr + k * 512 + j0);
        float4 wr1 = *(const float4*)(Wr + k * 512 + j0 + 4);
        al[0] += xs[k] * wl0.x; al[1] += xs[k] * wl0.y; al[2] += xs[k] * wl0.z; al[3] += xs[k] * wl0.w;
        al[4] += xs[k] * wl1.x; al[5] += xs[k] * wl1.y; al[6] += xs[k] * wl1.z; al[7] += xs[k] * wl1.w;
        ar[0] += xs[k] * wr0.x; ar[1] += xs[k] * wr0.y; ar[2] += xs[k] * wr0.z; ar[3] += xs[k] * wr0.w;
        ar[4] += xs[k] * wr1.x; ar[5] += xs[k] * wr1.y; ar[6] += xs[k] * wr1.z; ar[7] += xs[k] * wr1.w;
    }
    ushort4 o0, o1;
    o0.x = f2bf(al[0]); o0.y = f2bf(al[1]); o0.z = f2bf(al[2]); o0.w = f2bf(al[3]);
    o1.x = f2bf(al[4]); o1.y = f2bf(al[5]); o1.z = f2bf(al[6]); o1.w = f2bf(al[7]);
    *(ushort4*)(xl + (size_t)n * 512 + j0) = o0;
    *(ushort4*)(xl + (size_t)n * 512 + j0 + 4) = o1;
    o0.x = f2bf(ar[0]); o0.y = f2bf(ar[1]); o0.z = f2bf(ar[2]); o0.w = f2bf(ar[3]);
    o1.x = f2bf(ar[4]); o1.y = f2bf(ar[5]); o1.z = f2bf(ar[6]); o1.w = f2bf(ar[7]);
    *(ushort4*)(xr + (size_t)n * 512 + j0) = o0;
    *(ushort4*)(xr + (size_t)n * 512 + j0 + 4) = o1;
}

// ---------- 4 weight transposes in one dispatch ----------
__global__ __launch_bounds__(256) void k_wt4(const float* __restrict__ W0,
                                             const float* __restrict__ W1,
                                             const float* __restrict__ W2,
                                             const float* __restrict__ W3,
                                             unsigned short* __restrict__ Wt2,
                                             unsigned short* __restrict__ Wt3) {
    __shared__ float tile[64][65];
    int bid = blockIdx.x;
    int mat = bid >> 6, sub = bid & 63;
    const float* W = (mat == 0) ? W0 : (mat == 1) ? W1 : (mat == 2) ? W2 : W3;
    unsigned short* Wt = (mat == 0) ? Wt2 : (mat == 1) ? (Wt2 + 512 * 512)
                       : (mat == 2) ? Wt3 : (Wt3 + 512 * 512);
    int n0 = (sub & 7) * 64, k0 = (sub >> 3) * 64;
    int lr = threadIdx.x >> 4;
    int lc = (threadIdx.x & 15) << 2;
    for (int r = lr; r < 64; r += 16) {
        float4 v = *(const float4*)(W + (size_t)(k0 + r) * 512 + n0 + lc);
        tile[r][lc] = v.x; tile[r][lc + 1] = v.y; tile[r][lc + 2] = v.z; tile[r][lc + 3] = v.w;
    }
    __syncthreads();
    for (int r = lr; r < 64; r += 16) {
        ushort4 o;
        o.x = f2bf(tile[lc + 0][r]); o.y = f2bf(tile[lc + 1][r]);
        o.z = f2bf(tile[lc + 2][r]); o.w = f2bf(tile[lc + 3][r]);
        *(ushort4*)(Wt + (size_t)(n0 + r) * 512 + k0 + lc) = o;
    }
}

// ---------- bf16 MFMA GEMM (LDK=72 padded, VGPR staging, XCD-swizzled grid) ----------
#define BM 128
#define BN 128
#define BK 64
#define LDK 72

__global__ __launch_bounds__(256) void k_gemm_bf16(
        const unsigned short* __restrict__ Ab,
        const unsigned short* __restrict__ Bt,
        unsigned short* __restrict__ xl, unsigned short* __restrict__ xr) {
    __shared__ unsigned short As[BM * LDK];
    __shared__ unsigned short Bs[BN * LDK];
    int t = threadIdx.x;
    int bid = blockIdx.x;
    int xcd = bid & 7, r = bid >> 3;
    int m0 = (xcd * 16 + (r & 15)) * BM;
    int n0 = (r >> 4) * BN;
    int wid = t >> 6, lane = t & 63;
    int wm = (wid >> 1) * 64, wn = (wid & 1) * 64;
    int lrow = lane & 15, quad = lane >> 4;
    floatx4 acc[4][4] = {};
    for (int k0 = 0; k0 < 512; k0 += BK) {
        __syncthreads();
#pragma unroll
        for (int it = 0; it < 4; it++) {
            int cid = it * 256 + t;
            int row = cid >> 3, ch = cid & 7;
            uint4 va = *(const uint4*)(Ab + (size_t)(m0 + row) * 512 + k0 + ch * 8);
            *(uint4*)&As[row * LDK + ch * 8] = va;
            uint4 vb = *(const uint4*)(Bt + (size_t)(n0 + row) * 512 + k0 + ch * 8);
            *(uint4*)&Bs[row * LDK + ch * 8] = vb;
        }
        __syncthreads();
#pragma unroll
        for (int ko = 0; ko < 2; ko++) {
            bf16x8 af[4], bfr[4];
#pragma unroll
            for (int i = 0; i < 4; i++) {
                af[i]  = *(const bf16x8*)&As[(wm + i * 16 + lrow) * LDK + ko * 32 + quad * 8];
                bfr[i] = *(const bf16x8*)&Bs[(wn + i * 16 + lrow) * LDK + ko * 32 + quad * 8];
            }
#pragma unroll
            for (int i = 0; i < 4; i++)
#pragma unroll
                for (int j = 0; j < 4; j++)
                    acc[i][j] = __builtin_amdgcn_mfma_f32_16x16x32_bf16(af[i], bfr[j], acc[i][j], 0, 0, 0);
        }
    }
#pragma unroll
    for (int i = 0; i < 4; i++) {
        int row = m0 + wm + i * 16 + quad * 4;
#pragma unroll
        for (int j = 0; j < 4; j++) {
            int col = n0 + wn + j * 16 + lrow;
            unsigned short* dstp = (col < 512) ? (xl + (size_t)row * 512 + col)
                                               : (xr + (size_t)row * 512 + (col - 512));
#pragma unroll
            for (int rr = 0; rr < 4; rr++) dstp[(size_t)rr * 512] = f2bf(acc[i][j][rr]);
        }
    }
}

// ---------- fused GATv2 edge phase: 2-wide edges, no-max softmax, packed-fp32 math ----------
__global__ __launch_bounds__(256) void k_attn(
        const unsigned short* __restrict__ xl, const unsigned short* __restrict__ xr,
        const int* __restrict__ rp, const int* __restrict__ csrc,
        const float2* __restrict__ ce, const float* __restrict__ We,
        const float* __restrict__ att, const float* __restrict__ bias,
        float* __restrict__ out) {
    int n = blockIdx.x * 4 + (threadIdx.x >> 6);
    int lane = threadIdx.x & 63;
    int c0 = lane << 3;
    f32x2 wv0[4], wv1[4], av[4], rv[4];
    {
        float4 a = *(const float4*)(We + c0), b = *(const float4*)(We + c0 + 4);
        wv0[0] = (f32x2){a.x, a.y}; wv0[1] = (f32x2){a.z, a.w};
        wv0[2] = (f32x2){b.x, b.y}; wv0[3] = (f32x2){b.z, b.w};
        a = *(const float4*)(We + 512 + c0); b = *(const float4*)(We + 512 + c0 + 4);
        wv1[0] = (f32x2){a.x, a.y}; wv1[1] = (f32x2){a.z, a.w};
        wv1[2] = (f32x2){b.x, b.y}; wv1[3] = (f32x2){b.z, b.w};
        a = *(const float4*)(att + c0); b = *(const float4*)(att + c0 + 4);
        av[0] = (f32x2){a.x, a.y}; av[1] = (f32x2){a.z, a.w};
        av[2] = (f32x2){b.x, b.y}; av[3] = (f32x2){b.z, b.w};
        uint4 vr = *(const uint4*)(xr + (size_t)n * 512 + c0);
        unpk8v(vr, rv);
    }
    float l = 0.f;
    f32x2 acc[4] = {sp2(0.f), sp2(0.f), sp2(0.f), sp2(0.f)};
    int beg = rp[n], end = rp[n + 1];
    uint4 cv0 = {}, cv1 = {};
    float2 ce0 = {}, ce1 = {};
    if (beg < end) {
        int i1 = (beg + 1 < end) ? beg + 1 : end - 1;
        cv0 = *(const uint4*)(xl + (size_t)csrc[beg] * 512 + c0);
        ce0 = ce[beg];
        cv1 = *(const uint4*)(xl + (size_t)csrc[i1] * 512 + c0);
        ce1 = ce[i1];
    }
    int i = beg;
    for (; i + 1 < end; i += 2) {
        uint4 a0 = cv0, a1 = cv1;
        float2 d0 = ce0, d1 = ce1;
        int q0 = i + 2, q1 = i + 3;
        q0 = (q0 < end) ? q0 : end - 1;
        q1 = (q1 < end) ? q1 : end - 1;
        cv0 = *(const uint4*)(xl + (size_t)csrc[q0] * 512 + c0);
        ce0 = ce[q0];
        cv1 = *(const uint4*)(xl + (size_t)csrc[q1] * 512 + c0);
        ce1 = ce[q1];
        f32x2 lv0[4], lv1[4];
        unpk8v(a0, lv0);
        unpk8v(a1, lv1);
        f32x2 d0x = sp2(d0.x), d0y = sp2(d0.y), d1x = sp2(d1.x), d1y = sp2(d1.y);
        f32x2 p0v = sp2(0.f), p1v = sp2(0.f);
#pragma unroll
        for (int j = 0; j < 4; j++) {
            f32x2 v0 = lv0[j] + rv[j] + d0x * wv0[j] + d0y * wv1[j];
            f32x2 v1 = lv1[j] + rv[j] + d1x * wv0[j] + d1y * wv1[j];
            v0 = pkmax(v0, sp2(0.2f) * v0);   // leaky_relu(0.2)
            v1 = pkmax(v1, sp2(0.2f) * v1);
            p0v += av[j] * v0;
            p1v += av[j] * v1;
        }
        float p0 = p0v.x + p0v.y;
        float p1 = p1v.x + p1v.y;
        p0 += __shfl_xor(p0, 1);  p1 += __shfl_xor(p1, 1);
        p0 += __shfl_xor(p0, 2);  p1 += __shfl_xor(p1, 2);
        p0 += __shfl_xor(p0, 4);  p1 += __shfl_xor(p1, 4);
        p0 += __shfl_xor(p0, 8);  p1 += __shfl_xor(p1, 8);
        float w0 = __expf(fminf(p0, 60.f));
        float w1 = __expf(fminf(p1, 60.f));
        l += w0 + w1;
        f32x2 w0v = sp2(w0), w1v = sp2(w1);
#pragma unroll
        for (int j = 0; j < 4; j++)
            acc[j] += w0v * lv0[j] + w1v * lv1[j];
    }
    if (i < end) {  // odd tail: cv0 holds edge end-1
        f32x2 lv[4];
        unpk8v(cv0, lv);
        f32x2 dx = sp2(ce0.x), dy = sp2(ce0.y);
        f32x2 pv = sp2(0.f);
#pragma unroll
        for (int j = 0; j < 4; j++) {
            f32x2 v = lv[j] + rv[j] + dx * wv0[j] + dy * wv1[j];
            v = pkmax(v, sp2(0.2f) * v);
            pv += av[j] * v;
        }
        float p = pv.x + pv.y;
        p += __shfl_xor(p, 1);
        p += __shfl_xor(p, 2);
        p += __shfl_xor(p, 4);
        p += __shfl_xor(p, 8);
        float w = __expf(fminf(p, 60.f));
        l += w;
        f32x2 wv = sp2(w);
#pragma unroll
        for (int j = 0; j < 4; j++) acc[j] += wv * lv[j];
    }
    float inv = 1.f / (l + 1e-16f);
    const float* bb = bias + c0;
    float4 b0 = *(const float4*)bb, b1 = *(const float4*)(bb + 4);
    float* o = out + (size_t)n * 512 + c0;
    *(float4*)o = make_float4(acc[0].x * inv + b0.x, acc[0].y * inv + b0.y,
                              acc[1].x * inv + b0.z, acc[1].y * inv + b0.w);
    *(float4*)(o + 4) = make_float4(acc[2].x * inv + b1.x, acc[2].y * inv + b1.y,
                                    acc[3].x * inv + b1.z, acc[3].y * inv + b1.w);
}

// ---------- BN stats (pure atomics — R14 proven config) ----------
__global__ __launch_bounds__(256) void k_bnstat(const float* __restrict__ x,
                                                double* __restrict__ sum,
                                                double* __restrict__ sumsq) {
    int t = threadIdx.x;
    int r0 = blockIdx.x * 64;
    float s0 = 0.f, s1 = 0.f, q0 = 0.f, q1 = 0.f;
    for (int r = r0; r < r0 + 64; r++) {
        float v0 = x[(size_t)r * 512 + t];
        float v1 = x[(size_t)r * 512 + t + 256];
        s0 += v0; q0 += v0 * v0;
        s1 += v1; q1 += v1 * v1;
    }
    atomicAdd(sum + t, (double)s0);
    atomicAdd(sum + t + 256, (double)s1);
    atomicAdd(sumsq + t, (double)q0);
    atomicAdd(sumsq + t + 256, (double)q1);
}

// ---------- BN finalize+apply + ELU + optional residual ----------
__global__ void k_bnapply(const float* __restrict__ v, const float* __restrict__ resid,
                          const double* __restrict__ sum, const double* __restrict__ sumsq,
                          const float* __restrict__ g, const float* __restrict__ beta,
                          float* __restrict__ out, unsigned short* __restrict__ outb) {
    int i = (blockIdx.x * 256 + threadIdx.x) << 2;
    int c = i & 511;
    float4 vv = *(const float4*)(v + i);
    double2 s01 = *(const double2*)(sum + c);
    double2 s23 = *(const double2*)(sum + c + 2);
    double2 q01 = *(const double2*)(sumsq + c);
    double2 q23 = *(const double2*)(sumsq + c + 2);
    float4 gg = *(const float4*)(g + c);
    float4 be = *(const float4*)(beta + c);
    const double invN = 1.0 / NN;
    double mu0 = s01.x * invN, mu1 = s01.y * invN, mu2 = s23.x * invN, mu3 = s23.y * invN;
    float sc0 = gg.x * rsqrtf((float)(q01.x * invN - mu0 * mu0) + 1e-5f);
    float sc1 = gg.y * rsqrtf((float)(q01.y * invN - mu1 * mu1) + 1e-5f);
    float sc2 = gg.z * rsqrtf((float)(q23.x * invN - mu2 * mu2) + 1e-5f);
    float sc3 = gg.w * rsqrtf((float)(q23.y * invN - mu3 * mu3) + 1e-5f);
    float y0 = (vv.x - (float)mu0) * sc0 + be.x;
    float y1 = (vv.y - (float)mu1) * sc1 + be.y;
    float y2 = (vv.z - (float)mu2) * sc2 + be.z;
    float y3 = (vv.w - (float)mu3) * sc3 + be.w;
    y0 = y0 > 0.f ? y0 : expm1f(y0);
    y1 = y1 > 0.f ? y1 : expm1f(y1);
    y2 = y2 > 0.f ? y2 : expm1f(y2);
    y3 = y3 > 0.f ? y3 : expm1f(y3);
    if (resid) {
        float4 rr = *(const float4*)(resid + i);
        y0 += rr.x; y1 += rr.y; y2 += rr.z; y3 += rr.w;
    }
    if (out) *(float4*)(out + i) = make_float4(y0, y1, y2, y3);
    if (outb) {
        ushort4 o;
        o.x = f2bf(y0); o.y = f2bf(y1); o.z = f2bf(y2); o.w = f2bf(y3);
        *(ushort4*)(outb + i) = o;
    }
}

// ---------- pooling (reads bf16 x3) ----------
__global__ __launch_bounds__(256) void k_pool(const unsigned short* __restrict__ xb,
                                              const int* __restrict__ batch,
                                              float* __restrict__ pooled) {
    __shared__ float lacc[NG][512];
    int t = threadIdx.x;
    for (int i = t; i < NG * 512; i += 256) ((float*)lacc)[i] = 0.f;
    __syncthreads();
    int r0 = blockIdx.x * 64;
    for (int r = r0; r < r0 + 64; r++) {
        int g = batch[r];
        lacc[g][t]       += __uint_as_float((unsigned)xb[(size_t)r * 512 + t] << 16);
        lacc[g][t + 256] += __uint_as_float((unsigned)xb[(size_t)r * 512 + t + 256] << 16);
    }
    __syncthreads();
    int gmin = batch[r0], gmax = batch[r0 + 63];
    for (int g = gmin; g <= gmax; g++)
        for (int i = t; i < 512; i += 256)
            atomicAdd(&pooled[g * 512 + i], lacc[g][i]);
}

// ---------- MLP head ----------
__global__ __launch_bounds__(256) void k_mlp1(const float* __restrict__ pooled,
                                              const int* __restrict__ gcnt,
                                              const float* __restrict__ W1,
                                              const float* __restrict__ b1,
                                              float* __restrict__ h1) {
    int g = blockIdx.x, o = threadIdx.x;
    float dot = 0.f;
    for (int c = 0; c < 512; c++) dot += pooled[g * 512 + c] * W1[c * 256 + o];
    float s = dot / (float)gcnt[g] + b1[o];
    h1[g * 256 + o] = fmaxf(s, 0.f);
}

__global__ __launch_bounds__(256) void k_head(const float* __restrict__ h1,
                                              const float* __restrict__ W2,
                                              const float* __restrict__ b2,
                                              const float* __restrict__ clsW,
                                              const float* __restrict__ clsb,
                                              float* __restrict__ outp) {
    __shared__ float es[256];
    int g = blockIdx.x, o = threadIdx.x;
    float s = b2[o];
    for (int c = 0; c < 256; c++) s += h1[g * 256 + c] * W2[c * 256 + o];
    outp[NG * 12 + g * 256 + o] = s;  // emb
    es[o] = s;
    __syncthreads();
    if (o < 12) {
        float lg = clsb[o];
        for (int c = 0; c < 256; c++) lg += es[c] * clsW[c * 12 + o];
        outp[g * 12 + o] = lg;  // logits
    }
}

extern "C" void kernel_launch(void* const* d_in, const int* in_sizes, int n_in,
                              void* d_out, int out_size, void* d_ws, size_t ws_size,
                              hipStream_t stream) {
    const float* x     = (const float*)d_in[0];
    const float* ea    = (const float*)d_in[1];
    const int*   ei    = (const int*)d_in[2];
    const int*   batch = (const int*)d_in[3];
    const int* src = ei;
    const int* dst = ei + NE;

    float* base = (float*)d_ws;
    size_t off = 0;
    auto alloc = [&](size_t n) -> float* {   // n = FLOAT count
        float* p = base + off;
        off += (n + 255) & ~(size_t)255;
        return p;
    };
    unsigned short* xl  = (unsigned short*)alloc((size_t)NN * 256);  // [NN,512] bf16
    unsigned short* xr  = (unsigned short*)alloc((size_t)NN * 256);
    float*    bufA  = alloc((size_t)NN * 512);
    float*    bufB  = alloc((size_t)NN * 512);
    unsigned short* Xb  = (unsigned short*)alloc((size_t)NN * 256);  // [NN,512] bf16
    unsigned short* Wt2 = (unsigned short*)alloc(512 * 1024 / 2);
    unsigned short* Wt3 = (unsigned short*)alloc(512 * 1024 / 2);
    int*      cnt   = (int*)alloc(NN);
    int*      rp    = (int*)alloc(NN + 1);
    int*      offp  = (int*)alloc(NN);
    int*      csrc  = (int*)alloc(NE);
    float2*   ce    = (float2*)alloc((size_t)NE * 2);
    double*   bsum3 = (double*)alloc(3 * 2048);  // 3 layers x (bsum[512]|bsq[512]) doubles
    float*    pooled= alloc(NG * 512);
    int*      gcnt  = (int*)alloc(NG);
    float*    h1    = alloc(NG * 256);
    float*    outp  = (float*)d_out;  // [0,96): logits, [96,2144): emb

    hipMemsetAsync(cnt, 0, NN * sizeof(int), stream);
    hipMemsetAsync(bsum3, 0, 3 * 2048 * sizeof(float), stream);
    hipMemsetAsync(pooled, 0, NG * 512 * sizeof(float), stream);
    k_hist<<<NE / 256, 256, 0, stream>>>(dst, cnt);
    k_scan<<<1, 1024, 0, stream>>>(cnt, rp, offp, batch, gcnt);
    k_fill<<<NE / 256, 256, 0, stream>>>(dst, src, ea, offp, csrc, ce);
    k_wt4<<<256, 256, 0, stream>>>((const float*)d_in[11], (const float*)d_in[12],
                                   (const float*)d_in[18], (const float*)d_in[19], Wt2, Wt3);

    float* X = bufA;
    float* Y = bufB;
    for (int l = 0; l < 3; l++) {
        const float* Wl  = (const float*)d_in[4 + l * 7 + 0];
        const float* Wr  = (const float*)d_in[4 + l * 7 + 1];
        const float* We  = (const float*)d_in[4 + l * 7 + 2];
        const float* att = (const float*)d_in[4 + l * 7 + 3];
        const float* cb  = (const float*)d_in[4 + l * 7 + 4];
        const float* bg  = (const float*)d_in[4 + l * 7 + 5];
        const float* bb  = (const float*)d_in[4 + l * 7 + 6];

        if (l == 0) {
            k_lin1<<<NN / 4, 256, 0, stream>>>(x, Wl, Wr, xl, xr);
        } else {
            k_gemm_bf16<<<1024, 256, 0, stream>>>(Xb, (l == 1) ? Wt2 : Wt3, xl, xr);
        }
        k_attn<<<NN / 4, 256, 0, stream>>>(xl, xr, rp, csrc, ce, We, att, cb, Y);

        double* bsum = bsum3 + l * 1024;
        double* bsq  = bsum + 512;
        k_bnstat<<<256, 256, 0, stream>>>(Y, bsum, bsq);
        k_bnapply<<<(size_t)NN * 512 / 1024, 256, 0, stream>>>(
            Y, (l == 0) ? nullptr : X, bsum, bsq, bg, bb,
            (l < 2) ? Y : nullptr, Xb);

        float* tmp = X; X = Y; Y = tmp;
    }

    k_pool<<<NN / 64, 256, 0, stream>>>(Xb, batch, pooled);

    const float* geW1 = (const float*)d_in[25];
    const float* geb1 = (const float*)d_in[26];
    const float* geW2 = (const float*)d_in[27];
    const float* geb2 = (const float*)d_in[28];
    const float* clsW = (const float*)d_in[29];
    const float* clsb = (const float*)d_in[30];

    k_mlp1<<<NG, 256, 0, stream>>>(pooled, gcnt, geW1, geb1, h1);
    k_head<<<NG, 256, 0, stream>>>(h1, geW2, geb2, clsW, clsb, outp);
}

// Round 18
// 497.039 us; speedup vs baseline: 1.2797x; 1.0118x over previous
//
#include <hip/hip_runtime.h>
#include <math.h>

#define NN    16384
#define NE    262144
#define NHEAD 4
#define HC    512
#define NG    8

typedef __bf16 bf16x8 __attribute__((ext_vector_type(8)));
typedef float floatx4 __attribute__((ext_vector_type(4)));
typedef float f32x2 __attribute__((ext_vector_type(2)));

__device__ __forceinline__ f32x2 sp2(float s) { return (f32x2){s, s}; }
__device__ __forceinline__ f32x2 pkmax(f32x2 a, f32x2 b) {
    f32x2 r; r.x = fmaxf(a.x, b.x); r.y = fmaxf(a.y, b.y); return r;
}

__device__ __forceinline__ unsigned short f2bf(float f) {
    union { float f; unsigned u; } v{f};
    unsigned r = v.u + 0x7FFFu + ((v.u >> 16) & 1u);  // RNE
    return (unsigned short)(r >> 16);
}
__device__ __forceinline__ float bf2f(unsigned short b) {
    return __uint_as_float((unsigned)b << 16);
}

// unpack uint4 (8 packed bf16) -> 4 x f32x2 (channel pairs)
__device__ __forceinline__ void unpk8v(uint4 v, f32x2* f) {
    f[0] = (f32x2){__uint_as_float(v.x << 16), __uint_as_float(v.x & 0xFFFF0000u)};
    f[1] = (f32x2){__uint_as_float(v.y << 16), __uint_as_float(v.y & 0xFFFF0000u)};
    f[2] = (f32x2){__uint_as_float(v.z << 16), __uint_as_float(v.z & 0xFFFF0000u)};
    f[3] = (f32x2){__uint_as_float(v.w << 16), __uint_as_float(v.w & 0xFFFF0000u)};
}

// ---------- CSR build ----------
__global__ void k_hist(const int* __restrict__ dst, int* __restrict__ cnt) {
    int e = blockIdx.x * 256 + threadIdx.x;
    if (e < NE) atomicAdd(&cnt[dst[e]], 1);
}

__global__ __launch_bounds__(1024) void k_scan(const int* __restrict__ cnt,
                                               int* __restrict__ rp,
                                               int* __restrict__ offp,
                                               const int* __restrict__ batch,
                                               int* __restrict__ gcnt) {
    __shared__ int part[1024];
    int t = threadIdx.x;
    if (t < NG) {  // fused gcnt: batch sorted -> binary searches
        int lb[2];
#pragma unroll
        for (int q = 0; q < 2; q++) {
            int target = t + q;
            int lo = 0, hi = NN;
            while (lo < hi) {
                int mid = (lo + hi) >> 1;
                if (batch[mid] < target) lo = mid + 1; else hi = mid;
            }
            lb[q] = lo;
        }
        gcnt[t] = lb[1] - lb[0];
    }
    int base = t * 16;
    int loc[16];
    int s = 0;
#pragma unroll
    for (int i = 0; i < 16; i++) { loc[i] = s; s += cnt[base + i]; }
    part[t] = s;
    __syncthreads();
    for (int off = 1; off < 1024; off <<= 1) {
        int v = 0;
        if (t >= off) v = part[t - off];
        __syncthreads();
        if (t >= off) part[t] += v;
        __syncthreads();
    }
    int excl = (t == 0) ? 0 : part[t - 1];
#pragma unroll
    for (int i = 0; i < 16; i++) {
        int r = excl + loc[i];
        rp[base + i] = r;
        offp[base + i] = r;
    }
    if (t == 1023) rp[NN] = excl + s;
}

__global__ void k_fill(const int* __restrict__ dst, const int* __restrict__ src,
                       const float* __restrict__ ea, int* __restrict__ offp,
                       int* __restrict__ csrc, float2* __restrict__ ce) {
    int e = blockIdx.x * 256 + threadIdx.x;
    if (e < NE) {
        int d = dst[e];
        int pos = atomicAdd(&offp[d], 1);
        csrc[pos] = src[e];
        ce[pos] = *(const float2*)(ea + 2 * (size_t)e);
    }
}

// ---------- layer-1 linear (K=5), bf16 out, vectorized ----------
__global__ __launch_bounds__(256) void k_lin1(const float* __restrict__ x,
                                              const float* __restrict__ Wl,
                                              const float* __restrict__ Wr,
                                              unsigned short* __restrict__ xl,
                                              unsigned short* __restrict__ xr) {
    int n = blockIdx.x * 4 + (threadIdx.x >> 6);
    int lane = threadIdx.x & 63;
    int j0 = lane << 3;
    float xs[5];
#pragma unroll
    for (int k = 0; k < 5; k++) xs[k] = x[n * 5 + k];
    float al[8] = {}, ar[8] = {};
#pragma unroll
    for (int k = 0; k < 5; k++) {
        float4 wl0 = *(const float4*)(Wl + k * 512 + j0);
        float4 wl1 = *(const float4*)(Wl + k * 512 + j0 + 4);
        float4 wr0 = *(const float4*)(Wr + k * 512 + j0);
        float4 wr1 = *(const float4*)(Wr + k * 512 + j0 + 4);
        al[0] += xs[k] * wl0.x; al[1] += xs[k] * wl0.y; al[2] += xs[k] * wl0.z; al[3] += xs[k] * wl0.w;
        al[4] += xs[k] * wl1.x; al[5] += xs[k] * wl1.y; al[6] += xs[k] * wl1.z; al[7] += xs[k] * wl1.w;
        ar[0] += xs[k] * wr0.x; ar[1] += xs[k] * wr0.y; ar[2] += xs[k] * wr0.z; ar[3] += xs[k] * wr0.w;
        ar[4] += xs[k] * wr1.x; ar[5] += xs[k] * wr1.y; ar[6] += xs[k] * wr1.z; ar[7] += xs[k] * wr1.w;
    }
    ushort4 o0, o1;
    o0.x = f2bf(al[0]); o0.y = f2bf(al[1]); o0.z = f2bf(al[2]); o0.w = f2bf(al[3]);
    o1.x = f2bf(al[4]); o1.y = f2bf(al[5]); o1.z = f2bf(al[6]); o1.w = f2bf(al[7]);
    *(ushort4*)(xl + (size_t)n * 512 + j0) = o0;
    *(ushort4*)(xl + (size_t)n * 512 + j0 + 4) = o1;
    o0.x = f2bf(ar[0]); o0.y = f2bf(ar[1]); o0.z = f2bf(ar[2]); o0.w = f2bf(ar[3]);
    o1.x = f2bf(ar[4]); o1.y = f2bf(ar[5]); o1.z = f2bf(ar[6]); o1.w = f2bf(ar[7]);
    *(ushort4*)(xr + (size_t)n * 512 + j0) = o0;
    *(ushort4*)(xr + (size_t)n * 512 + j0 + 4) = o1;
}

// ---------- 4 weight transposes in one dispatch ----------
__global__ __launch_bounds__(256) void k_wt4(const float* __restrict__ W0,
                                             const float* __restrict__ W1,
                                             const float* __restrict__ W2,
                                             const float* __restrict__ W3,
                                             unsigned short* __restrict__ Wt2,
                                             unsigned short* __restrict__ Wt3) {
    __shared__ float tile[64][65];
    int bid = blockIdx.x;
    int mat = bid >> 6, sub = bid & 63;
    const float* W = (mat == 0) ? W0 : (mat == 1) ? W1 : (mat == 2) ? W2 : W3;
    unsigned short* Wt = (mat == 0) ? Wt2 : (mat == 1) ? (Wt2 + 512 * 512)
                       : (mat == 2) ? Wt3 : (Wt3 + 512 * 512);
    int n0 = (sub & 7) * 64, k0 = (sub >> 3) * 64;
    int lr = threadIdx.x >> 4;
    int lc = (threadIdx.x & 15) << 2;
    for (int r = lr; r < 64; r += 16) {
        float4 v = *(const float4*)(W + (size_t)(k0 + r) * 512 + n0 + lc);
        tile[r][lc] = v.x; tile[r][lc + 1] = v.y; tile[r][lc + 2] = v.z; tile[r][lc + 3] = v.w;
    }
    __syncthreads();
    for (int r = lr; r < 64; r += 16) {
        ushort4 o;
        o.x = f2bf(tile[lc + 0][r]); o.y = f2bf(tile[lc + 1][r]);
        o.z = f2bf(tile[lc + 2][r]); o.w = f2bf(tile[lc + 3][r]);
        *(ushort4*)(Wt + (size_t)(n0 + r) * 512 + k0 + lc) = o;
    }
}

// ---------- bf16 MFMA GEMM (LDK=72 padded, VGPR staging, XCD-swizzled grid) ----------
#define BM 128
#define BN 128
#define BK 64
#define LDK 72

__global__ __launch_bounds__(256) void k_gemm_bf16(
        const unsigned short* __restrict__ Ab,
        const unsigned short* __restrict__ Bt,
        unsigned short* __restrict__ xl, unsigned short* __restrict__ xr) {
    __shared__ unsigned short As[BM * LDK];
    __shared__ unsigned short Bs[BN * LDK];
    int t = threadIdx.x;
    int bid = blockIdx.x;
    int xcd = bid & 7, r = bid >> 3;
    int m0 = (xcd * 16 + (r & 15)) * BM;
    int n0 = (r >> 4) * BN;
    int wid = t >> 6, lane = t & 63;
    int wm = (wid >> 1) * 64, wn = (wid & 1) * 64;
    int lrow = lane & 15, quad = lane >> 4;
    floatx4 acc[4][4] = {};
    for (int k0 = 0; k0 < 512; k0 += BK) {
        __syncthreads();
#pragma unroll
        for (int it = 0; it < 4; it++) {
            int cid = it * 256 + t;
            int row = cid >> 3, ch = cid & 7;
            uint4 va = *(const uint4*)(Ab + (size_t)(m0 + row) * 512 + k0 + ch * 8);
            *(uint4*)&As[row * LDK + ch * 8] = va;
            uint4 vb = *(const uint4*)(Bt + (size_t)(n0 + row) * 512 + k0 + ch * 8);
            *(uint4*)&Bs[row * LDK + ch * 8] = vb;
        }
        __syncthreads();
#pragma unroll
        for (int ko = 0; ko < 2; ko++) {
            bf16x8 af[4], bfr[4];
#pragma unroll
            for (int i = 0; i < 4; i++) {
                af[i]  = *(const bf16x8*)&As[(wm + i * 16 + lrow) * LDK + ko * 32 + quad * 8];
                bfr[i] = *(const bf16x8*)&Bs[(wn + i * 16 + lrow) * LDK + ko * 32 + quad * 8];
            }
#pragma unroll
            for (int i = 0; i < 4; i++)
#pragma unroll
                for (int j = 0; j < 4; j++)
                    acc[i][j] = __builtin_amdgcn_mfma_f32_16x16x32_bf16(af[i], bfr[j], acc[i][j], 0, 0, 0);
        }
    }
#pragma unroll
    for (int i = 0; i < 4; i++) {
        int row = m0 + wm + i * 16 + quad * 4;
#pragma unroll
        for (int j = 0; j < 4; j++) {
            int col = n0 + wn + j * 16 + lrow;
            unsigned short* dstp = (col < 512) ? (xl + (size_t)row * 512 + col)
                                               : (xr + (size_t)row * 512 + (col - 512));
#pragma unroll
            for (int rr = 0; rr < 4; rr++) dstp[(size_t)rr * 512] = f2bf(acc[i][j][rr]);
        }
    }
}

// ---------- fused GATv2 edge phase: 2-wide, no-max softmax, packed math, bf16 out ----------
__global__ __launch_bounds__(256) void k_attn(
        const unsigned short* __restrict__ xl, const unsigned short* __restrict__ xr,
        const int* __restrict__ rp, const int* __restrict__ csrc,
        const float2* __restrict__ ce, const float* __restrict__ We,
        const float* __restrict__ att, const float* __restrict__ bias,
        unsigned short* __restrict__ out) {
    int n = blockIdx.x * 4 + (threadIdx.x >> 6);
    int lane = threadIdx.x & 63;
    int c0 = lane << 3;
    f32x2 wv0[4], wv1[4], av[4], rv[4];
    {
        float4 a = *(const float4*)(We + c0), b = *(const float4*)(We + c0 + 4);
        wv0[0] = (f32x2){a.x, a.y}; wv0[1] = (f32x2){a.z, a.w};
        wv0[2] = (f32x2){b.x, b.y}; wv0[3] = (f32x2){b.z, b.w};
        a = *(const float4*)(We + 512 + c0); b = *(const float4*)(We + 512 + c0 + 4);
        wv1[0] = (f32x2){a.x, a.y}; wv1[1] = (f32x2){a.z, a.w};
        wv1[2] = (f32x2){b.x, b.y}; wv1[3] = (f32x2){b.z, b.w};
        a = *(const float4*)(att + c0); b = *(const float4*)(att + c0 + 4);
        av[0] = (f32x2){a.x, a.y}; av[1] = (f32x2){a.z, a.w};
        av[2] = (f32x2){b.x, b.y}; av[3] = (f32x2){b.z, b.w};
        uint4 vr = *(const uint4*)(xr + (size_t)n * 512 + c0);
        unpk8v(vr, rv);
    }
    float l = 0.f;
    f32x2 acc[4] = {sp2(0.f), sp2(0.f), sp2(0.f), sp2(0.f)};
    int beg = rp[n], end = rp[n + 1];
    uint4 cv0 = {}, cv1 = {};
    float2 ce0 = {}, ce1 = {};
    if (beg < end) {
        int i1 = (beg + 1 < end) ? beg + 1 : end - 1;
        cv0 = *(const uint4*)(xl + (size_t)csrc[beg] * 512 + c0);
        ce0 = ce[beg];
        cv1 = *(const uint4*)(xl + (size_t)csrc[i1] * 512 + c0);
        ce1 = ce[i1];
    }
    int i = beg;
    for (; i + 1 < end; i += 2) {
        uint4 a0 = cv0, a1 = cv1;
        float2 d0 = ce0, d1 = ce1;
        int q0 = i + 2, q1 = i + 3;
        q0 = (q0 < end) ? q0 : end - 1;
        q1 = (q1 < end) ? q1 : end - 1;
        cv0 = *(const uint4*)(xl + (size_t)csrc[q0] * 512 + c0);
        ce0 = ce[q0];
        cv1 = *(const uint4*)(xl + (size_t)csrc[q1] * 512 + c0);
        ce1 = ce[q1];
        f32x2 lv0[4], lv1[4];
        unpk8v(a0, lv0);
        unpk8v(a1, lv1);
        f32x2 d0x = sp2(d0.x), d0y = sp2(d0.y), d1x = sp2(d1.x), d1y = sp2(d1.y);
        f32x2 p0v = sp2(0.f), p1v = sp2(0.f);
#pragma unroll
        for (int j = 0; j < 4; j++) {
            f32x2 v0 = lv0[j] + rv[j] + d0x * wv0[j] + d0y * wv1[j];
            f32x2 v1 = lv1[j] + rv[j] + d1x * wv0[j] + d1y * wv1[j];
            v0 = pkmax(v0, sp2(0.2f) * v0);   // leaky_relu(0.2)
            v1 = pkmax(v1, sp2(0.2f) * v1);
            p0v += av[j] * v0;
            p1v += av[j] * v1;
        }
        float p0 = p0v.x + p0v.y;
        float p1 = p1v.x + p1v.y;
        p0 += __shfl_xor(p0, 1);  p1 += __shfl_xor(p1, 1);
        p0 += __shfl_xor(p0, 2);  p1 += __shfl_xor(p1, 2);
        p0 += __shfl_xor(p0, 4);  p1 += __shfl_xor(p1, 4);
        p0 += __shfl_xor(p0, 8);  p1 += __shfl_xor(p1, 8);
        float w0 = __expf(fminf(p0, 60.f));
        float w1 = __expf(fminf(p1, 60.f));
        l += w0 + w1;
        f32x2 w0v = sp2(w0), w1v = sp2(w1);
#pragma unroll
        for (int j = 0; j < 4; j++)
            acc[j] += w0v * lv0[j] + w1v * lv1[j];
    }
    if (i < end) {  // odd tail: cv0 holds edge end-1
        f32x2 lv[4];
        unpk8v(cv0, lv);
        f32x2 dx = sp2(ce0.x), dy = sp2(ce0.y);
        f32x2 pv = sp2(0.f);
#pragma unroll
        for (int j = 0; j < 4; j++) {
            f32x2 v = lv[j] + rv[j] + dx * wv0[j] + dy * wv1[j];
            v = pkmax(v, sp2(0.2f) * v);
            pv += av[j] * v;
        }
        float p = pv.x + pv.y;
        p += __shfl_xor(p, 1);
        p += __shfl_xor(p, 2);
        p += __shfl_xor(p, 4);
        p += __shfl_xor(p, 8);
        float w = __expf(fminf(p, 60.f));
        l += w;
        f32x2 wv = sp2(w);
#pragma unroll
        for (int j = 0; j < 4; j++) acc[j] += wv * lv[j];
    }
    float inv = 1.f / (l + 1e-16f);
    const float* bb = bias + c0;
    float4 b0 = *(const float4*)bb, b1 = *(const float4*)(bb + 4);
    ushort4 o0, o1;
    o0.x = f2bf(acc[0].x * inv + b0.x); o0.y = f2bf(acc[0].y * inv + b0.y);
    o0.z = f2bf(acc[1].x * inv + b0.z); o0.w = f2bf(acc[1].y * inv + b0.w);
    o1.x = f2bf(acc[2].x * inv + b1.x); o1.y = f2bf(acc[2].y * inv + b1.y);
    o1.z = f2bf(acc[3].x * inv + b1.z); o1.w = f2bf(acc[3].y * inv + b1.w);
    *(ushort4*)(out + (size_t)n * 512 + c0) = o0;
    *(ushort4*)(out + (size_t)n * 512 + c0 + 4) = o1;
}

// ---------- BN stats (bf16 input; thread t covers channels 2t,2t+1) ----------
__global__ __launch_bounds__(256) void k_bnstat(const unsigned short* __restrict__ xb,
                                                double* __restrict__ sum,
                                                double* __restrict__ sumsq) {
    int t = threadIdx.x;
    int r0 = blockIdx.x * 64;
    int c2 = t << 1;
    float s0 = 0.f, s1 = 0.f, q0 = 0.f, q1 = 0.f;
    for (int r = r0; r < r0 + 64; r++) {
        unsigned u = *(const unsigned*)(xb + (size_t)r * 512 + c2);
        float v0 = __uint_as_float(u << 16);
        float v1 = __uint_as_float(u & 0xFFFF0000u);
        s0 += v0; q0 += v0 * v0;
        s1 += v1; q1 += v1 * v1;
    }
    atomicAdd(sum + c2, (double)s0);
    atomicAdd(sum + c2 + 1, (double)s1);
    atomicAdd(sumsq + c2, (double)q0);
    atomicAdd(sumsq + c2 + 1, (double)q1);
}

// ---------- BN finalize+apply + ELU + optional residual (all bf16 I/O) ----------
__global__ void k_bnapply(const unsigned short* __restrict__ v,
                          const unsigned short* __restrict__ resid,
                          const double* __restrict__ sum, const double* __restrict__ sumsq,
                          const float* __restrict__ g, const float* __restrict__ beta,
                          unsigned short* __restrict__ outb) {
    int i = (blockIdx.x * 256 + threadIdx.x) << 2;
    int c = i & 511;
    ushort4 vu = *(const ushort4*)(v + i);
    double2 s01 = *(const double2*)(sum + c);
    double2 s23 = *(const double2*)(sum + c + 2);
    double2 q01 = *(const double2*)(sumsq + c);
    double2 q23 = *(const double2*)(sumsq + c + 2);
    float4 gg = *(const float4*)(g + c);
    float4 be = *(const float4*)(beta + c);
    const double invN = 1.0 / NN;
    double mu0 = s01.x * invN, mu1 = s01.y * invN, mu2 = s23.x * invN, mu3 = s23.y * invN;
    float sc0 = gg.x * rsqrtf((float)(q01.x * invN - mu0 * mu0) + 1e-5f);
    float sc1 = gg.y * rsqrtf((float)(q01.y * invN - mu1 * mu1) + 1e-5f);
    float sc2 = gg.z * rsqrtf((float)(q23.x * invN - mu2 * mu2) + 1e-5f);
    float sc3 = gg.w * rsqrtf((float)(q23.y * invN - mu3 * mu3) + 1e-5f);
    float y0 = (bf2f(vu.x) - (float)mu0) * sc0 + be.x;
    float y1 = (bf2f(vu.y) - (float)mu1) * sc1 + be.y;
    float y2 = (bf2f(vu.z) - (float)mu2) * sc2 + be.z;
    float y3 = (bf2f(vu.w) - (float)mu3) * sc3 + be.w;
    y0 = y0 > 0.f ? y0 : expm1f(y0);
    y1 = y1 > 0.f ? y1 : expm1f(y1);
    y2 = y2 > 0.f ? y2 : expm1f(y2);
    y3 = y3 > 0.f ? y3 : expm1f(y3);
    if (resid) {
        ushort4 ru = *(const ushort4*)(resid + i);
        y0 += bf2f(ru.x); y1 += bf2f(ru.y); y2 += bf2f(ru.z); y3 += bf2f(ru.w);
    }
    ushort4 o;
    o.x = f2bf(y0); o.y = f2bf(y1); o.z = f2bf(y2); o.w = f2bf(y3);
    *(ushort4*)(outb + i) = o;
}

// ---------- pooling (reads bf16 x3) ----------
__global__ __launch_bounds__(256) void k_pool(const unsigned short* __restrict__ xb,
                                              const int* __restrict__ batch,
                                              float* __restrict__ pooled) {
    __shared__ float lacc[NG][512];
    int t = threadIdx.x;
    for (int i = t; i < NG * 512; i += 256) ((float*)lacc)[i] = 0.f;
    __syncthreads();
    int r0 = blockIdx.x * 64;
    for (int r = r0; r < r0 + 64; r++) {
        int g = batch[r];
        lacc[g][t]       += __uint_as_float((unsigned)xb[(size_t)r * 512 + t] << 16);
        lacc[g][t + 256] += __uint_as_float((unsigned)xb[(size_t)r * 512 + t + 256] << 16);
    }
    __syncthreads();
    int gmin = batch[r0], gmax = batch[r0 + 63];
    for (int g = gmin; g <= gmax; g++)
        for (int i = t; i < 512; i += 256)
            atomicAdd(&pooled[g * 512 + i], lacc[g][i]);
}

// ---------- MLP head ----------
__global__ __launch_bounds__(256) void k_mlp1(const float* __restrict__ pooled,
                                              const int* __restrict__ gcnt,
                                              const float* __restrict__ W1,
                                              const float* __restrict__ b1,
                                              float* __restrict__ h1) {
    int g = blockIdx.x, o = threadIdx.x;
    float dot = 0.f;
    for (int c = 0; c < 512; c++) dot += pooled[g * 512 + c] * W1[c * 256 + o];
    float s = dot / (float)gcnt[g] + b1[o];
    h1[g * 256 + o] = fmaxf(s, 0.f);
}

__global__ __launch_bounds__(256) void k_head(const float* __restrict__ h1,
                                              const float* __restrict__ W2,
                                              const float* __restrict__ b2,
                                              const float* __restrict__ clsW,
                                              const float* __restrict__ clsb,
                                              float* __restrict__ outp) {
    __shared__ float es[256];
    int g = blockIdx.x, o = threadIdx.x;
    float s = b2[o];
    for (int c = 0; c < 256; c++) s += h1[g * 256 + c] * W2[c * 256 + o];
    outp[NG * 12 + g * 256 + o] = s;  // emb
    es[o] = s;
    __syncthreads();
    if (o < 12) {
        float lg = clsb[o];
        for (int c = 0; c < 256; c++) lg += es[c] * clsW[c * 12 + o];
        outp[g * 12 + o] = lg;  // logits
    }
}

extern "C" void kernel_launch(void* const* d_in, const int* in_sizes, int n_in,
                              void* d_out, int out_size, void* d_ws, size_t ws_size,
                              hipStream_t stream) {
    const float* x     = (const float*)d_in[0];
    const float* ea    = (const float*)d_in[1];
    const int*   ei    = (const int*)d_in[2];
    const int*   batch = (const int*)d_in[3];
    const int* src = ei;
    const int* dst = ei + NE;

    float* base = (float*)d_ws;
    size_t off = 0;
    auto alloc = [&](size_t n) -> float* {   // n = FLOAT count
        float* p = base + off;
        off += (n + 255) & ~(size_t)255;
        return p;
    };
    unsigned short* xl  = (unsigned short*)alloc((size_t)NN * 256);  // [NN,512] bf16
    unsigned short* xr  = (unsigned short*)alloc((size_t)NN * 256);
    unsigned short* Yb  = (unsigned short*)alloc((size_t)NN * 256);  // attn out bf16
    unsigned short* XbA = (unsigned short*)alloc((size_t)NN * 256);  // layer-out ping
    unsigned short* XbB = (unsigned short*)alloc((size_t)NN * 256);  // layer-out pong
    unsigned short* Wt2 = (unsigned short*)alloc(512 * 1024 / 2);
    unsigned short* Wt3 = (unsigned short*)alloc(512 * 1024 / 2);
    int*      cnt   = (int*)alloc(NN);
    int*      rp    = (int*)alloc(NN + 1);
    int*      offp  = (int*)alloc(NN);
    int*      csrc  = (int*)alloc(NE);
    float2*   ce    = (float2*)alloc((size_t)NE * 2);
    double*   bsum3 = (double*)alloc(3 * 2048);  // 3 layers x (bsum[512]|bsq[512]) doubles
    float*    pooled= alloc(NG * 512);
    int*      gcnt  = (int*)alloc(NG);
    float*    h1    = alloc(NG * 256);
    float*    outp  = (float*)d_out;  // [0,96): logits, [96,2144): emb

    hipMemsetAsync(cnt, 0, NN * sizeof(int), stream);
    hipMemsetAsync(bsum3, 0, 3 * 2048 * sizeof(float), stream);
    hipMemsetAsync(pooled, 0, NG * 512 * sizeof(float), stream);
    k_hist<<<NE / 256, 256, 0, stream>>>(dst, cnt);
    k_scan<<<1, 1024, 0, stream>>>(cnt, rp, offp, batch, gcnt);
    k_fill<<<NE / 256, 256, 0, stream>>>(dst, src, ea, offp, csrc, ce);
    k_wt4<<<256, 256, 0, stream>>>((const float*)d_in[11], (const float*)d_in[12],
                                   (const float*)d_in[18], (const float*)d_in[19], Wt2, Wt3);

    unsigned short* X = XbA;   // current layer output
    unsigned short* Xp = XbB;  // previous layer output (residual)
    for (int l = 0; l < 3; l++) {
        const float* Wl  = (const float*)d_in[4 + l * 7 + 0];
        const float* Wr  = (const float*)d_in[4 + l * 7 + 1];
        const float* We  = (const float*)d_in[4 + l * 7 + 2];
        const float* att = (const float*)d_in[4 + l * 7 + 3];
        const float* cb  = (const float*)d_in[4 + l * 7 + 4];
        const float* bg  = (const float*)d_in[4 + l * 7 + 5];
        const float* bb  = (const float*)d_in[4 + l * 7 + 6];

        if (l == 0) {
            k_lin1<<<NN / 4, 256, 0, stream>>>(x, Wl, Wr, xl, xr);
        } else {
            k_gemm_bf16<<<1024, 256, 0, stream>>>(Xp, (l == 1) ? Wt2 : Wt3, xl, xr);
        }
        k_attn<<<NN / 4, 256, 0, stream>>>(xl, xr, rp, csrc, ce, We, att, cb, Yb);

        double* bsum = bsum3 + l * 1024;
        double* bsq  = bsum + 512;
        k_bnstat<<<256, 256, 0, stream>>>(Yb, bsum, bsq);
        k_bnapply<<<(size_t)NN * 512 / 1024, 256, 0, stream>>>(
            Yb, (l == 0) ? nullptr : Xp, bsum, bsq, bg, bb, X);

        unsigned short* tmp = Xp; Xp = X; X = tmp;  // Xp now holds this layer's output
    }

    k_pool<<<NN / 64, 256, 0, stream>>>(Xp, batch, pooled);

    const float* geW1 = (const float*)d_in[25];
    const float* geb1 = (const float*)d_in[26];
    const float* geW2 = (const float*)d_in[27];
    const float* geb2 = (const float*)d_in[28];
    const float* clsW = (const float*)d_in[29];
    const float* clsb = (const float*)d_in[30];

    k_mlp1<<<NG, 256, 0, stream>>>(pooled, gcnt, geW1, geb1, h1);
    k_head<<<NG, 256, 0, stream>>>(h1, geW2, geb2, clsW, clsb, outp);
}

// Round 19
// 496.670 us; speedup vs baseline: 1.2807x; 1.0007x over previous
//
#include <hip/hip_runtime.h>
#include <math.h>

#define NN    16384
#define NE    262144
#define NHEAD 4
#define HC    512
#define NG    8

typedef __bf16 bf16x8 __attribute__((ext_vector_type(8)));
typedef float floatx4 __attribute__((ext_vector_type(4)));
typedef float f32x2 __attribute__((ext_vector_type(2)));

__device__ __forceinline__ f32x2 sp2(float s) { return (f32x2){s, s}; }
__device__ __forceinline__ f32x2 pkmax(f32x2 a, f32x2 b) {
    f32x2 r; r.x = fmaxf(a.x, b.x); r.y = fmaxf(a.y, b.y); return r;
}

__device__ __forceinline__ unsigned short f2bf(float f) {
    union { float f; unsigned u; } v{f};
    unsigned r = v.u + 0x7FFFu + ((v.u >> 16) & 1u);  // RNE
    return (unsigned short)(r >> 16);
}
__device__ __forceinline__ float bf2f(unsigned short b) {
    return __uint_as_float((unsigned)b << 16);
}

// unpack uint4 (8 packed bf16) -> 4 x f32x2 (channel pairs)
__device__ __forceinline__ void unpk8v(uint4 v, f32x2* f) {
    f[0] = (f32x2){__uint_as_float(v.x << 16), __uint_as_float(v.x & 0xFFFF0000u)};
    f[1] = (f32x2){__uint_as_float(v.y << 16), __uint_as_float(v.y & 0xFFFF0000u)};
    f[2] = (f32x2){__uint_as_float(v.z << 16), __uint_as_float(v.z & 0xFFFF0000u)};
    f[3] = (f32x2){__uint_as_float(v.w << 16), __uint_as_float(v.w & 0xFFFF0000u)};
}

// ---------- CSR build ----------
__global__ void k_hist(const int* __restrict__ dst, int* __restrict__ cnt) {
    int e = blockIdx.x * 256 + threadIdx.x;
    if (e < NE) atomicAdd(&cnt[dst[e]], 1);
}

__global__ __launch_bounds__(1024) void k_scan(const int* __restrict__ cnt,
                                               int* __restrict__ rp,
                                               int* __restrict__ offp,
                                               const int* __restrict__ batch,
                                               int* __restrict__ gcnt) {
    __shared__ int part[1024];
    int t = threadIdx.x;
    if (t < NG) {  // fused gcnt: batch sorted -> binary searches
        int lb[2];
#pragma unroll
        for (int q = 0; q < 2; q++) {
            int target = t + q;
            int lo = 0, hi = NN;
            while (lo < hi) {
                int mid = (lo + hi) >> 1;
                if (batch[mid] < target) lo = mid + 1; else hi = mid;
            }
            lb[q] = lo;
        }
        gcnt[t] = lb[1] - lb[0];
    }
    int base = t * 16;
    int loc[16];
    int s = 0;
#pragma unroll
    for (int i = 0; i < 16; i++) { loc[i] = s; s += cnt[base + i]; }
    part[t] = s;
    __syncthreads();
    for (int off = 1; off < 1024; off <<= 1) {
        int v = 0;
        if (t >= off) v = part[t - off];
        __syncthreads();
        if (t >= off) part[t] += v;
        __syncthreads();
    }
    int excl = (t == 0) ? 0 : part[t - 1];
#pragma unroll
    for (int i = 0; i < 16; i++) {
        int r = excl + loc[i];
        rp[base + i] = r;
        offp[base + i] = r;
    }
    if (t == 1023) rp[NN] = excl + s;
}

__global__ void k_fill(const int* __restrict__ dst, const int* __restrict__ src,
                       const float* __restrict__ ea, int* __restrict__ offp,
                       int* __restrict__ csrc, float2* __restrict__ ce) {
    int e = blockIdx.x * 256 + threadIdx.x;
    if (e < NE) {
        int d = dst[e];
        int pos = atomicAdd(&offp[d], 1);
        csrc[pos] = src[e];
        ce[pos] = *(const float2*)(ea + 2 * (size_t)e);
    }
}

// ---------- layer-1 linear (K=5), bf16 out, vectorized ----------
__global__ __launch_bounds__(256) void k_lin1(const float* __restrict__ x,
                                              const float* __restrict__ Wl,
                                              const float* __restrict__ Wr,
                                              unsigned short* __restrict__ xl,
                                              unsigned short* __restrict__ xr) {
    int n = blockIdx.x * 4 + (threadIdx.x >> 6);
    int lane = threadIdx.x & 63;
    int j0 = lane << 3;
    float xs[5];
#pragma unroll
    for (int k = 0; k < 5; k++) xs[k] = x[n * 5 + k];
    float al[8] = {}, ar[8] = {};
#pragma unroll
    for (int k = 0; k < 5; k++) {
        float4 wl0 = *(const float4*)(Wl + k * 512 + j0);
        float4 wl1 = *(const float4*)(Wl + k * 512 + j0 + 4);
        float4 wr0 = *(const float4*)(Wr + k * 512 + j0);
        float4 wr1 = *(const float4*)(Wr + k * 512 + j0 + 4);
        al[0] += xs[k] * wl0.x; al[1] += xs[k] * wl0.y; al[2] += xs[k] * wl0.z; al[3] += xs[k] * wl0.w;
        al[4] += xs[k] * wl1.x; al[5] += xs[k] * wl1.y; al[6] += xs[k] * wl1.z; al[7] += xs[k] * wl1.w;
        ar[0] += xs[k] * wr0.x; ar[1] += xs[k] * wr0.y; ar[2] += xs[k] * wr0.z; ar[3] += xs[k] * wr0.w;
        ar[4] += xs[k] * wr1.x; ar[5] += xs[k] * wr1.y; ar[6] += xs[k] * wr1.z; ar[7] += xs[k] * wr1.w;
    }
    ushort4 o0, o1;
    o0.x = f2bf(al[0]); o0.y = f2bf(al[1]); o0.z = f2bf(al[2]); o0.w = f2bf(al[3]);
    o1.x = f2bf(al[4]); o1.y = f2bf(al[5]); o1.z = f2bf(al[6]); o1.w = f2bf(al[7]);
    *(ushort4*)(xl + (size_t)n * 512 + j0) = o0;
    *(ushort4*)(xl + (size_t)n * 512 + j0 + 4) = o1;
    o0.x = f2bf(ar[0]); o0.y = f2bf(ar[1]); o0.z = f2bf(ar[2]); o0.w = f2bf(ar[3]);
    o1.x = f2bf(ar[4]); o1.y = f2bf(ar[5]); o1.z = f2bf(ar[6]); o1.w = f2bf(ar[7]);
    *(ushort4*)(xr + (size_t)n * 512 + j0) = o0;
    *(ushort4*)(xr + (size_t)n * 512 + j0 + 4) = o1;
}

// ---------- 4 weight transposes in one dispatch ----------
__global__ __launch_bounds__(256) void k_wt4(const float* __restrict__ W0,
                                             const float* __restrict__ W1,
                                             const float* __restrict__ W2,
                                             const float* __restrict__ W3,
                                             unsigned short* __restrict__ Wt2,
                                             unsigned short* __restrict__ Wt3) {
    __shared__ float tile[64][65];
    int bid = blockIdx.x;
    int mat = bid >> 6, sub = bid & 63;
    const float* W = (mat == 0) ? W0 : (mat == 1) ? W1 : (mat == 2) ? W2 : W3;
    unsigned short* Wt = (mat == 0) ? Wt2 : (mat == 1) ? (Wt2 + 512 * 512)
                       : (mat == 2) ? Wt3 : (Wt3 + 512 * 512);
    int n0 = (sub & 7) * 64, k0 = (sub >> 3) * 64;
    int lr = threadIdx.x >> 4;
    int lc = (threadIdx.x & 15) << 2;
    for (int r = lr; r < 64; r += 16) {
        float4 v = *(const float4*)(W + (size_t)(k0 + r) * 512 + n0 + lc);
        tile[r][lc] = v.x; tile[r][lc + 1] = v.y; tile[r][lc + 2] = v.z; tile[r][lc + 3] = v.w;
    }
    __syncthreads();
    for (int r = lr; r < 64; r += 16) {
        ushort4 o;
        o.x = f2bf(tile[lc + 0][r]); o.y = f2bf(tile[lc + 1][r]);
        o.z = f2bf(tile[lc + 2][r]); o.w = f2bf(tile[lc + 3][r]);
        *(ushort4*)(Wt + (size_t)(n0 + r) * 512 + k0 + lc) = o;
    }
}

// ---------- bf16 MFMA GEMM (LDK=72 padded, VGPR staging, XCD-swizzled grid) ----------
#define BM 128
#define BN 128
#define BK 64
#define LDK 72

__global__ __launch_bounds__(256) void k_gemm_bf16(
        const unsigned short* __restrict__ Ab,
        const unsigned short* __restrict__ Bt,
        unsigned short* __restrict__ xl, unsigned short* __restrict__ xr) {
    __shared__ unsigned short As[BM * LDK];
    __shared__ unsigned short Bs[BN * LDK];
    int t = threadIdx.x;
    int bid = blockIdx.x;
    int xcd = bid & 7, r = bid >> 3;
    int m0 = (xcd * 16 + (r & 15)) * BM;
    int n0 = (r >> 4) * BN;
    int wid = t >> 6, lane = t & 63;
    int wm = (wid >> 1) * 64, wn = (wid & 1) * 64;
    int lrow = lane & 15, quad = lane >> 4;
    floatx4 acc[4][4] = {};
    for (int k0 = 0; k0 < 512; k0 += BK) {
        __syncthreads();
#pragma unroll
        for (int it = 0; it < 4; it++) {
            int cid = it * 256 + t;
            int row = cid >> 3, ch = cid & 7;
            uint4 va = *(const uint4*)(Ab + (size_t)(m0 + row) * 512 + k0 + ch * 8);
            *(uint4*)&As[row * LDK + ch * 8] = va;
            uint4 vb = *(const uint4*)(Bt + (size_t)(n0 + row) * 512 + k0 + ch * 8);
            *(uint4*)&Bs[row * LDK + ch * 8] = vb;
        }
        __syncthreads();
#pragma unroll
        for (int ko = 0; ko < 2; ko++) {
            bf16x8 af[4], bfr[4];
#pragma unroll
            for (int i = 0; i < 4; i++) {
                af[i]  = *(const bf16x8*)&As[(wm + i * 16 + lrow) * LDK + ko * 32 + quad * 8];
                bfr[i] = *(const bf16x8*)&Bs[(wn + i * 16 + lrow) * LDK + ko * 32 + quad * 8];
            }
#pragma unroll
            for (int i = 0; i < 4; i++)
#pragma unroll
                for (int j = 0; j < 4; j++)
                    acc[i][j] = __builtin_amdgcn_mfma_f32_16x16x32_bf16(af[i], bfr[j], acc[i][j], 0, 0, 0);
        }
    }
#pragma unroll
    for (int i = 0; i < 4; i++) {
        int row = m0 + wm + i * 16 + quad * 4;
#pragma unroll
        for (int j = 0; j < 4; j++) {
            int col = n0 + wn + j * 16 + lrow;
            unsigned short* dstp = (col < 512) ? (xl + (size_t)row * 512 + col)
                                               : (xr + (size_t)row * 512 + (col - 512));
#pragma unroll
            for (int rr = 0; rr < 4; rr++) dstp[(size_t)rr * 512] = f2bf(acc[i][j][rr]);
        }
    }
}

// ---------- fused GATv2 edge phase: 2-wide, no-max softmax, packed math, bf16 out ----------
__global__ __launch_bounds__(256) void k_attn(
        const unsigned short* __restrict__ xl, const unsigned short* __restrict__ xr,
        const int* __restrict__ rp, const int* __restrict__ csrc,
        const float2* __restrict__ ce, const float* __restrict__ We,
        const float* __restrict__ att, const float* __restrict__ bias,
        unsigned short* __restrict__ out) {
    int n = blockIdx.x * 4 + (threadIdx.x >> 6);
    int lane = threadIdx.x & 63;
    int c0 = lane << 3;
    f32x2 wv0[4], wv1[4], av[4], rv[4];
    {
        float4 a = *(const float4*)(We + c0), b = *(const float4*)(We + c0 + 4);
        wv0[0] = (f32x2){a.x, a.y}; wv0[1] = (f32x2){a.z, a.w};
        wv0[2] = (f32x2){b.x, b.y}; wv0[3] = (f32x2){b.z, b.w};
        a = *(const float4*)(We + 512 + c0); b = *(const float4*)(We + 512 + c0 + 4);
        wv1[0] = (f32x2){a.x, a.y}; wv1[1] = (f32x2){a.z, a.w};
        wv1[2] = (f32x2){b.x, b.y}; wv1[3] = (f32x2){b.z, b.w};
        a = *(const float4*)(att + c0); b = *(const float4*)(att + c0 + 4);
        av[0] = (f32x2){a.x, a.y}; av[1] = (f32x2){a.z, a.w};
        av[2] = (f32x2){b.x, b.y}; av[3] = (f32x2){b.z, b.w};
        uint4 vr = *(const uint4*)(xr + (size_t)n * 512 + c0);
        unpk8v(vr, rv);
    }
    float l = 0.f;
    f32x2 acc[4] = {sp2(0.f), sp2(0.f), sp2(0.f), sp2(0.f)};
    int beg = rp[n], end = rp[n + 1];
    uint4 cv0 = {}, cv1 = {};
    float2 ce0 = {}, ce1 = {};
    if (beg < end) {
        int i1 = (beg + 1 < end) ? beg + 1 : end - 1;
        cv0 = *(const uint4*)(xl + (size_t)csrc[beg] * 512 + c0);
        ce0 = ce[beg];
        cv1 = *(const uint4*)(xl + (size_t)csrc[i1] * 512 + c0);
        ce1 = ce[i1];
    }
    int i = beg;
    for (; i + 1 < end; i += 2) {
        uint4 a0 = cv0, a1 = cv1;
        float2 d0 = ce0, d1 = ce1;
        int q0 = i + 2, q1 = i + 3;
        q0 = (q0 < end) ? q0 : end - 1;
        q1 = (q1 < end) ? q1 : end - 1;
        cv0 = *(const uint4*)(xl + (size_t)csrc[q0] * 512 + c0);
        ce0 = ce[q0];
        cv1 = *(const uint4*)(xl + (size_t)csrc[q1] * 512 + c0);
        ce1 = ce[q1];
        f32x2 lv0[4], lv1[4];
        unpk8v(a0, lv0);
        unpk8v(a1, lv1);
        f32x2 d0x = sp2(d0.x), d0y = sp2(d0.y), d1x = sp2(d1.x), d1y = sp2(d1.y);
        f32x2 p0v = sp2(0.f), p1v = sp2(0.f);
#pragma unroll
        for (int j = 0; j < 4; j++) {
            f32x2 v0 = lv0[j] + rv[j] + d0x * wv0[j] + d0y * wv1[j];
            f32x2 v1 = lv1[j] + rv[j] + d1x * wv0[j] + d1y * wv1[j];
            v0 = pkmax(v0, sp2(0.2f) * v0);   // leaky_relu(0.2)
            v1 = pkmax(v1, sp2(0.2f) * v1);
            p0v += av[j] * v0;
            p1v += av[j] * v1;
        }
        float p0 = p0v.x + p0v.y;
        float p1 = p1v.x + p1v.y;
        p0 += __shfl_xor(p0, 1);  p1 += __shfl_xor(p1, 1);
        p0 += __shfl_xor(p0, 2);  p1 += __shfl_xor(p1, 2);
        p0 += __shfl_xor(p0, 4);  p1 += __shfl_xor(p1, 4);
        p0 += __shfl_xor(p0, 8);  p1 += __shfl_xor(p1, 8);
        float w0 = __expf(fminf(p0, 60.f));
        float w1 = __expf(fminf(p1, 60.f));
        l += w0 + w1;
        f32x2 w0v = sp2(w0), w1v = sp2(w1);
#pragma unroll
        for (int j = 0; j < 4; j++)
            acc[j] += w0v * lv0[j] + w1v * lv1[j];
    }
    if (i < end) {  // odd tail: cv0 holds edge end-1
        f32x2 lv[4];
        unpk8v(cv0, lv);
        f32x2 dx = sp2(ce0.x), dy = sp2(ce0.y);
        f32x2 pv = sp2(0.f);
#pragma unroll
        for (int j = 0; j < 4; j++) {
            f32x2 v = lv[j] + rv[j] + dx * wv0[j] + dy * wv1[j];
            v = pkmax(v, sp2(0.2f) * v);
            pv += av[j] * v;
        }
        float p = pv.x + pv.y;
        p += __shfl_xor(p, 1);
        p += __shfl_xor(p, 2);
        p += __shfl_xor(p, 4);
        p += __shfl_xor(p, 8);
        float w = __expf(fminf(p, 60.f));
        l += w;
        f32x2 wv = sp2(w);
#pragma unroll
        for (int j = 0; j < 4; j++) acc[j] += wv * lv[j];
    }
    float inv = 1.f / (l + 1e-16f);
    const float* bb = bias + c0;
    float4 b0 = *(const float4*)bb, b1 = *(const float4*)(bb + 4);
    ushort4 o0, o1;
    o0.x = f2bf(acc[0].x * inv + b0.x); o0.y = f2bf(acc[0].y * inv + b0.y);
    o0.z = f2bf(acc[1].x * inv + b0.z); o0.w = f2bf(acc[1].y * inv + b0.w);
    o1.x = f2bf(acc[2].x * inv + b1.x); o1.y = f2bf(acc[2].y * inv + b1.y);
    o1.z = f2bf(acc[3].x * inv + b1.z); o1.w = f2bf(acc[3].y * inv + b1.w);
    *(ushort4*)(out + (size_t)n * 512 + c0) = o0;
    *(ushort4*)(out + (size_t)n * 512 + c0 + 4) = o1;
}

// ---------- BN stats (bf16 input; thread t covers channels 2t,2t+1) ----------
__global__ __launch_bounds__(256) void k_bnstat(const unsigned short* __restrict__ xb,
                                                double* __restrict__ sum,
                                                double* __restrict__ sumsq) {
    int t = threadIdx.x;
    int r0 = blockIdx.x * 64;
    int c2 = t << 1;
    float s0 = 0.f, s1 = 0.f, q0 = 0.f, q1 = 0.f;
    for (int r = r0; r < r0 + 64; r++) {
        unsigned u = *(const unsigned*)(xb + (size_t)r * 512 + c2);
        float v0 = __uint_as_float(u << 16);
        float v1 = __uint_as_float(u & 0xFFFF0000u);
        s0 += v0; q0 += v0 * v0;
        s1 += v1; q1 += v1 * v1;
    }
    atomicAdd(sum + c2, (double)s0);
    atomicAdd(sum + c2 + 1, (double)s1);
    atomicAdd(sumsq + c2, (double)q0);
    atomicAdd(sumsq + c2 + 1, (double)q1);
}

// ---------- BN finalize+apply + ELU + optional residual (all bf16 I/O) ----------
__global__ void k_bnapply(const unsigned short* __restrict__ v,
                          const unsigned short* __restrict__ resid,
                          const double* __restrict__ sum, const double* __restrict__ sumsq,
                          const float* __restrict__ g, const float* __restrict__ beta,
                          unsigned short* __restrict__ outb) {
    int i = (blockIdx.x * 256 + threadIdx.x) << 2;
    int c = i & 511;
    ushort4 vu = *(const ushort4*)(v + i);
    double2 s01 = *(const double2*)(sum + c);
    double2 s23 = *(const double2*)(sum + c + 2);
    double2 q01 = *(const double2*)(sumsq + c);
    double2 q23 = *(const double2*)(sumsq + c + 2);
    float4 gg = *(const float4*)(g + c);
    float4 be = *(const float4*)(beta + c);
    const double invN = 1.0 / NN;
    double mu0 = s01.x * invN, mu1 = s01.y * invN, mu2 = s23.x * invN, mu3 = s23.y * invN;
    float sc0 = gg.x * rsqrtf((float)(q01.x * invN - mu0 * mu0) + 1e-5f);
    float sc1 = gg.y * rsqrtf((float)(q01.y * invN - mu1 * mu1) + 1e-5f);
    float sc2 = gg.z * rsqrtf((float)(q23.x * invN - mu2 * mu2) + 1e-5f);
    float sc3 = gg.w * rsqrtf((float)(q23.y * invN - mu3 * mu3) + 1e-5f);
    float y0 = (bf2f(vu.x) - (float)mu0) * sc0 + be.x;
    float y1 = (bf2f(vu.y) - (float)mu1) * sc1 + be.y;
    float y2 = (bf2f(vu.z) - (float)mu2) * sc2 + be.z;
    float y3 = (bf2f(vu.w) - (float)mu3) * sc3 + be.w;
    y0 = y0 > 0.f ? y0 : expm1f(y0);
    y1 = y1 > 0.f ? y1 : expm1f(y1);
    y2 = y2 > 0.f ? y2 : expm1f(y2);
    y3 = y3 > 0.f ? y3 : expm1f(y3);
    if (resid) {
        ushort4 ru = *(const ushort4*)(resid + i);
        y0 += bf2f(ru.x); y1 += bf2f(ru.y); y2 += bf2f(ru.z); y3 += bf2f(ru.w);
    }
    ushort4 o;
    o.x = f2bf(y0); o.y = f2bf(y1); o.z = f2bf(y2); o.w = f2bf(y3);
    *(ushort4*)(outb + i) = o;
}

// ---------- pooling (bf16 in, dword loads: thread t covers channels 2t,2t+1) ----------
__global__ __launch_bounds__(256) void k_pool(const unsigned short* __restrict__ xb,
                                              const int* __restrict__ batch,
                                              float* __restrict__ pooled) {
    __shared__ float lacc[NG][512];
    int t = threadIdx.x;
    for (int i = t; i < NG * 512; i += 256) ((float*)lacc)[i] = 0.f;
    __syncthreads();
    int r0 = blockIdx.x * 64;
    int c2 = t << 1;
    for (int r = r0; r < r0 + 64; r++) {
        int g = batch[r];
        unsigned u = *(const unsigned*)(xb + (size_t)r * 512 + c2);
        lacc[g][c2]     += __uint_as_float(u << 16);
        lacc[g][c2 + 1] += __uint_as_float(u & 0xFFFF0000u);
    }
    __syncthreads();
    int gmin = batch[r0], gmax = batch[r0 + 63];
    for (int g = gmin; g <= gmax; g++)
        for (int i = t; i < 512; i += 256)
            atomicAdd(&pooled[g * 512 + i], lacc[g][i]);
}

// ---------- fused MLP head: pooled -> h1 -> emb -> logits (one dispatch) ----------
__global__ __launch_bounds__(256) void k_head2(const float* __restrict__ pooled,
                                               const int* __restrict__ gcnt,
                                               const float* __restrict__ W1,
                                               const float* __restrict__ b1,
                                               const float* __restrict__ W2,
                                               const float* __restrict__ b2,
                                               const float* __restrict__ clsW,
                                               const float* __restrict__ clsb,
                                               float* __restrict__ outp) {
    __shared__ float h1s[256];
    __shared__ float es[256];
    int g = blockIdx.x, o = threadIdx.x;
    float dot = 0.f;
    for (int c = 0; c < 512; c++) dot += pooled[g * 512 + c] * W1[c * 256 + o];
    h1s[o] = fmaxf(dot / (float)gcnt[g] + b1[o], 0.f);
    __syncthreads();
    float s = b2[o];
    for (int c = 0; c < 256; c++) s += h1s[c] * W2[c * 256 + o];
    outp[NG * 12 + g * 256 + o] = s;  // emb
    es[o] = s;
    __syncthreads();
    if (o < 12) {
        float lg = clsb[o];
        for (int c = 0; c < 256; c++) lg += es[c] * clsW[c * 12 + o];
        outp[g * 12 + o] = lg;  // logits
    }
}

extern "C" void kernel_launch(void* const* d_in, const int* in_sizes, int n_in,
                              void* d_out, int out_size, void* d_ws, size_t ws_size,
                              hipStream_t stream) {
    const float* x     = (const float*)d_in[0];
    const float* ea    = (const float*)d_in[1];
    const int*   ei    = (const int*)d_in[2];
    const int*   batch = (const int*)d_in[3];
    const int* src = ei;
    const int* dst = ei + NE;

    float* base = (float*)d_ws;
    size_t off = 0;
    auto alloc = [&](size_t n) -> float* {   // n = FLOAT count (256-aligned)
        float* p = base + off;
        off += (n + 255) & ~(size_t)255;
        return p;
    };
    unsigned short* xl  = (unsigned short*)alloc((size_t)NN * 256);  // [NN,512] bf16
    unsigned short* xr  = (unsigned short*)alloc((size_t)NN * 256);
    unsigned short* Yb  = (unsigned short*)alloc((size_t)NN * 256);  // attn out bf16
    unsigned short* XbA = (unsigned short*)alloc((size_t)NN * 256);  // layer-out ping
    unsigned short* XbB = (unsigned short*)alloc((size_t)NN * 256);  // layer-out pong
    unsigned short* Wt2 = (unsigned short*)alloc(512 * 1024 / 2);
    unsigned short* Wt3 = (unsigned short*)alloc(512 * 1024 / 2);
    int*      rp    = (int*)alloc(NN + 1);
    int*      offp  = (int*)alloc(NN);
    int*      csrc  = (int*)alloc(NE);
    float2*   ce    = (float2*)alloc((size_t)NE * 2);
    // --- zero-init region: cnt | bsum3 | pooled (contiguous, one memset) ---
    int*      cnt   = (int*)alloc(NN);           // 16384 floats
    double*   bsum3 = (double*)alloc(3 * 2048);  // 6144 floats
    float*    pooled= alloc(NG * 512);           // 4096 floats
    // --- end zero-init region (26624 floats total) ---
    int*      gcnt  = (int*)alloc(NG);
    float*    outp  = (float*)d_out;  // [0,96): logits, [96,2144): emb

    hipMemsetAsync(cnt, 0, 26624 * sizeof(float), stream);  // cnt+bsum3+pooled
    k_hist<<<NE / 256, 256, 0, stream>>>(dst, cnt);
    k_scan<<<1, 1024, 0, stream>>>(cnt, rp, offp, batch, gcnt);
    k_fill<<<NE / 256, 256, 0, stream>>>(dst, src, ea, offp, csrc, ce);
    k_wt4<<<256, 256, 0, stream>>>((const float*)d_in[11], (const float*)d_in[12],
                                   (const float*)d_in[18], (const float*)d_in[19], Wt2, Wt3);

    unsigned short* X = XbA;   // current layer output
    unsigned short* Xp = XbB;  // previous layer output (residual)
    for (int l = 0; l < 3; l++) {
        const float* Wl  = (const float*)d_in[4 + l * 7 + 0];
        const float* Wr  = (const float*)d_in[4 + l * 7 + 1];
        const float* We  = (const float*)d_in[4 + l * 7 + 2];
        const float* att = (const float*)d_in[4 + l * 7 + 3];
        const float* cb  = (const float*)d_in[4 + l * 7 + 4];
        const float* bg  = (const float*)d_in[4 + l * 7 + 5];
        const float* bb  = (const float*)d_in[4 + l * 7 + 6];

        if (l == 0) {
            k_lin1<<<NN / 4, 256, 0, stream>>>(x, Wl, Wr, xl, xr);
        } else {
            k_gemm_bf16<<<1024, 256, 0, stream>>>(Xp, (l == 1) ? Wt2 : Wt3, xl, xr);
        }
        k_attn<<<NN / 4, 256, 0, stream>>>(xl, xr, rp, csrc, ce, We, att, cb, Yb);

        double* bsum = bsum3 + l * 1024;
        double* bsq  = bsum + 512;
        k_bnstat<<<256, 256, 0, stream>>>(Yb, bsum, bsq);
        k_bnapply<<<(size_t)NN * 512 / 1024, 256, 0, stream>>>(
            Yb, (l == 0) ? nullptr : Xp, bsum, bsq, bg, bb, X);

        unsigned short* tmp = Xp; Xp = X; X = tmp;  // Xp now holds this layer's output
    }

    k_pool<<<NN / 64, 256, 0, stream>>>(Xp, batch, pooled);

    const float* geW1 = (const float*)d_in[25];
    const float* geb1 = (const float*)d_in[26];
    const float* geW2 = (const float*)d_in[27];
    const float* geb2 = (const float*)d_in[28];
    const float* clsW = (const float*)d_in[29];
    const float* clsb = (const float*)d_in[30];

    k_head2<<<NG, 256, 0, stream>>>(pooled, gcnt, geW1, geb1, geW2, geb2, clsW, clsb, outp);
}